// Round 1
// baseline (429.523 us; speedup 1.0000x reference)
//
#include <hip/hip_runtime.h>
#include <stdint.h>
#include <stddef.h>

#define Bd 2
#define Sd 2048
#define Ed 2048
#define Hd 16
#define Dd 128

typedef unsigned short u16;
typedef __attribute__((ext_vector_type(8))) short short8;
typedef __attribute__((ext_vector_type(4))) float f32x4;

__device__ __forceinline__ u16 f2bf(float f) {
  union { float f; uint32_t u; } v; v.f = f;
  uint32_t r = v.u + 0x7FFFu + ((v.u >> 16) & 1u);
  return (u16)(r >> 16);
}
__device__ __forceinline__ float bf2f(u16 h) {
  union { uint32_t u; float f; } v; v.u = ((uint32_t)h) << 16;
  return v.f;
}
__device__ __forceinline__ void gll16(const void* g, void* lds) {
  __builtin_amdgcn_global_load_lds(
      (const __attribute__((address_space(1))) void*)g,
      (__attribute__((address_space(3))) void*)lds, 16, 0, 0);
}
template<int C> __device__ __forceinline__ float dppmv(float x) {
  return __builtin_bit_cast(float,
      __builtin_amdgcn_update_dpp(0, __builtin_bit_cast(int, x), C, 0xF, 0xF, false));
}
__device__ __forceinline__ float rmax16(float x) {
  x = fmaxf(x, dppmv<0x121>(x)); x = fmaxf(x, dppmv<0x122>(x));
  x = fmaxf(x, dppmv<0x124>(x)); x = fmaxf(x, dppmv<0x128>(x));
  return x;
}
__device__ __forceinline__ float rsum16(float x) {
  x += dppmv<0x121>(x); x += dppmv<0x122>(x);
  x += dppmv<0x124>(x); x += dppmv<0x128>(x);
  return x;
}
#define MFMA(a,b,c) __builtin_amdgcn_mfma_f32_16x16x32_bf16((a),(b),(c),0,0,0)

// ---------------- pre-pass: fp32 -> bf16 hi/lo split ----------------
__global__ void k_split(const float* __restrict__ src, u16* __restrict__ hi,
                        u16* __restrict__ lo, int n4) {
  const int stride = gridDim.x * blockDim.x;
  for (int i = blockIdx.x * blockDim.x + threadIdx.x; i < n4; i += stride) {
    const float4 v = ((const float4*)src)[i];
    const u16 h0 = f2bf(v.x), h1 = f2bf(v.y), h2 = f2bf(v.z), h3 = f2bf(v.w);
    ((ushort4*)hi)[i] = make_ushort4(h0, h1, h2, h3);
    ((ushort4*)lo)[i] = make_ushort4(f2bf(v.x - bf2f(h0)), f2bf(v.y - bf2f(h1)),
                                     f2bf(v.z - bf2f(h2)), f2bf(v.w - bf2f(h3)));
  }
}
__global__ void k_cvt(const float* __restrict__ src, u16* __restrict__ dst, int n4) {
  const int stride = gridDim.x * blockDim.x;
  for (int i = blockIdx.x * blockDim.x + threadIdx.x; i < n4; i += stride) {
    const float4 v = ((const float4*)src)[i];
    ((ushort4*)dst)[i] = make_ushort4(f2bf(v.x), f2bf(v.y), f2bf(v.z), f2bf(v.w));
  }
}

// ---------------- QKV projection: C[m,f] = sum_e x[m,e] * W[f,e] ----------------
// z=0 -> Q (split output), z=1 -> K (split), z=2 -> V (single-pass, bf16 out)
__global__ __launch_bounds__(256, 2) void k_qkv(
    const u16* __restrict__ xh, const u16* __restrict__ xl,
    const u16* __restrict__ wh_all, const u16* __restrict__ wl_all,
    u16* __restrict__ Qh, u16* __restrict__ Ql,
    u16* __restrict__ Kh, u16* __restrict__ Kl, u16* __restrict__ Vb) {
  __shared__ __align__(16) u16 Ah[128*64];
  __shared__ __align__(16) u16 Al[128*64];
  __shared__ __align__(16) u16 Bh[128*64];
  __shared__ __align__(16) u16 Bl[128*64];
  const int z = blockIdx.z;
  const bool splt = (z != 2);
  const u16* wh = wh_all + (size_t)z * Ed * Ed;
  const u16* wl = wl_all + (size_t)z * Ed * Ed;
  const int n0 = blockIdx.x * 128, m0 = blockIdx.y * 128;
  const int tid = threadIdx.x, wv = tid >> 6, ln = tid & 63;
  const int wm = wv >> 1, wn = wv & 1;
  const f32x4 fz = {0.f, 0.f, 0.f, 0.f};
  f32x4 acc[4][4];
#pragma unroll
  for (int m = 0; m < 4; ++m)
#pragma unroll
    for (int n = 0; n < 4; ++n) acc[m][n] = fz;

  for (int k0 = 0; k0 < Ed; k0 += 64) {
#pragma unroll
    for (int i = 0; i < 4; ++i) {
      const int lin = i * 4096 + wv * 1024 + ln * 16;  // byte offset in 16KB tile
      const int row = lin >> 7;                         // 128B per row (64 bf16)
      const int cb = lin & 127;
      const int gc = cb ^ ((row & 7) << 4);             // pre-swizzled source
      const size_t goffA = (size_t)(m0 + row) * (Ed * 2) + (size_t)k0 * 2 + gc;
      const size_t goffB = (size_t)(n0 + row) * (Ed * 2) + (size_t)k0 * 2 + gc;
      const int lb = i * 4096 + wv * 1024;              // wave-uniform LDS base
      gll16((const char*)xh + goffA, (char*)Ah + lb);
      gll16((const char*)wh + goffB, (char*)Bh + lb);
      if (splt) {
        gll16((const char*)xl + goffA, (char*)Al + lb);
        gll16((const char*)wl + goffB, (char*)Bl + lb);
      }
    }
    __syncthreads();
#pragma unroll
    for (int kk = 0; kk < 2; ++kk) {
      short8 a_h[4], a_l[4], b_h[4], b_l[4];
#pragma unroll
      for (int m = 0; m < 4; ++m) {
        const int row = wm * 64 + m * 16 + (ln & 15);
        const int cb = (kk * 64 + (ln >> 4) * 16) ^ ((row & 7) << 4);
        a_h[m] = *(const short8*)((const char*)Ah + row * 128 + cb);
        if (splt) a_l[m] = *(const short8*)((const char*)Al + row * 128 + cb);
      }
#pragma unroll
      for (int n = 0; n < 4; ++n) {
        const int row = wn * 64 + n * 16 + (ln & 15);
        const int cb = (kk * 64 + (ln >> 4) * 16) ^ ((row & 7) << 4);
        b_h[n] = *(const short8*)((const char*)Bh + row * 128 + cb);
        if (splt) b_l[n] = *(const short8*)((const char*)Bl + row * 128 + cb);
      }
#pragma unroll
      for (int m = 0; m < 4; ++m)
#pragma unroll
        for (int n = 0; n < 4; ++n) {
          acc[m][n] = MFMA(a_h[m], b_h[n], acc[m][n]);
          if (splt) {
            acc[m][n] = MFMA(a_h[m], b_l[n], acc[m][n]);
            acc[m][n] = MFMA(a_l[m], b_h[n], acc[m][n]);
          }
        }
    }
    __syncthreads();
  }
  // epilogue: write to (B,H,S,D); Q/K re-split to hi/lo bf16, V single bf16
#pragma unroll
  for (int m = 0; m < 4; ++m)
#pragma unroll
    for (int n = 0; n < 4; ++n)
#pragma unroll
      for (int r = 0; r < 4; ++r) {
        const int mg = m0 + wm * 64 + m * 16 + (ln >> 4) * 4 + r;
        const int f = n0 + wn * 64 + n * 16 + (ln & 15);
        const int b = mg >> 11, s = mg & (Sd - 1);
        const int h = f >> 7, d = f & (Dd - 1);
        const size_t o = (((size_t)b * Hd + h) * Sd + s) * Dd + d;
        const float v = acc[m][n][r];
        if (z == 0) { const u16 hh = f2bf(v); Qh[o] = hh; Ql[o] = f2bf(v - bf2f(hh)); }
        else if (z == 1) { const u16 hh = f2bf(v); Kh[o] = hh; Kl[o] = f2bf(v - bf2f(hh)); }
        else { Vb[o] = f2bf(v); }
      }
}

// ---------------- causal flash attention (no 1/sqrt(d) scale) ----------------
// block: 4 waves, Q-tile 128 rows (32/wave), KV-tile 64
__global__ __launch_bounds__(256, 2) void k_attn(
    const u16* __restrict__ Qh, const u16* __restrict__ Ql,
    const u16* __restrict__ Kh, const u16* __restrict__ Kl,
    const u16* __restrict__ Vb, u16* __restrict__ ctx) {
  __shared__ __align__(16) char smem[51200];
  char* KhsB = smem;             // 16384 B  [64][128] bf16, swizzled
  char* KlsB = smem + 16384;     // 16384 B
  char* VtB  = smem + 32768;     // 18432 B  [128 d][72 k] bf16, swizzled
  char* PlB  = smem;             // 18432 B, ALIASES K region (barrier-separated)

  const int bh = blockIdx.x;                       // b*H + h
  const int qt = (int)gridDim.y - 1 - blockIdx.y;  // heavy tiles dispatched first
  const int tid = threadIdx.x, wv = tid >> 6, ln = tid & 63;
  const int q0 = qt * 128 + wv * 32;
  const size_t headoff = (size_t)bh * Sd * Dd;

  // Q fragments in registers (hi/lo), rows q0 .. q0+31 (mi=0,1)
  short8 qfh[2][4], qfl[2][4];
#pragma unroll
  for (int mi = 0; mi < 2; ++mi)
#pragma unroll
    for (int c = 0; c < 4; ++c) {
      const size_t off = headoff + (size_t)(q0 + mi * 16 + (ln & 15)) * Dd + c * 32 + (ln >> 4) * 8;
      qfh[mi][c] = *(const short8*)(Qh + off);
      qfl[mi][c] = *(const short8*)(Ql + off);
    }

  const f32x4 fz = {0.f, 0.f, 0.f, 0.f};
  f32x4 acc_o[2][8];
  float m_run[2][4], l_run[2][4];
#pragma unroll
  for (int mi = 0; mi < 2; ++mi) {
#pragma unroll
    for (int n = 0; n < 8; ++n) acc_o[mi][n] = fz;
#pragma unroll
    for (int r = 0; r < 4; ++r) { m_run[mi][r] = -1e30f; l_run[mi][r] = 0.f; }
  }

  const int ktmax = 2 * qt + 1;
  for (int kt = 0; kt <= ktmax; ++kt) {
    // ---- stage K hi/lo (global_load_lds, pre-swizzled source) ----
    const size_t ktile = (headoff + (size_t)kt * 64 * Dd) * 2;  // bytes
#pragma unroll
    for (int i = 0; i < 4; ++i) {
      const int lin = i * 4096 + wv * 1024 + ln * 16;
      const int row = lin >> 8;               // 256B per row (128 bf16)
      const int cb = lin & 255;
      const int gc = cb ^ ((row & 7) << 4);
      const size_t go = ktile + (size_t)row * 256 + gc;
      const int lb = i * 4096 + wv * 1024;
      gll16((const char*)Kh + go, KhsB + lb);
      gll16((const char*)Kl + go, KlsB + lb);
    }
    // ---- stage V transposed: Vt[d][k], stride 72 bf16, k-slot XOR swizzle ----
#pragma unroll
    for (int p = 0; p < 4; ++p) {
      const int rr = (tid >> 4) + 16 * p;          // kv row 0..63
      const int d0 = (tid & 15) * 8;               // 8 contiguous d
      const short8 vv = *(const short8*)(Vb + headoff + (size_t)(kt * 64 + rr) * Dd + d0);
#pragma unroll
      for (int j = 0; j < 8; ++j) {
        const int d = d0 + j;
        *(u16*)(VtB + d * 144 + ((rr * 2) ^ (((d >> 3) & 7) << 4))) = (u16)vv[j];
      }
    }
    __syncthreads();

    const bool skip = (kt * 64) > (q0 + 31);  // wave fully masked

    // ---- scores: S = Q K^T (3-pass split) ----
    f32x4 sc[2][4];
#pragma unroll
    for (int mi = 0; mi < 2; ++mi)
#pragma unroll
      for (int t = 0; t < 4; ++t) sc[mi][t] = fz;
    if (!skip) {
#pragma unroll
      for (int t = 0; t < 4; ++t)
#pragma unroll
        for (int c = 0; c < 4; ++c) {
          const int row = t * 16 + (ln & 15);
          const int cb = (c * 64 + (ln >> 4) * 16) ^ ((row & 7) << 4);
          const short8 kh8 = *(const short8*)(KhsB + row * 256 + cb);
          const short8 kl8 = *(const short8*)(KlsB + row * 256 + cb);
#pragma unroll
          for (int mi = 0; mi < 2; ++mi) {
            sc[mi][t] = MFMA(qfh[mi][c], kh8, sc[mi][t]);
            sc[mi][t] = MFMA(qfh[mi][c], kl8, sc[mi][t]);
            sc[mi][t] = MFMA(qfl[mi][c], kh8, sc[mi][t]);
          }
        }
      if (kt >= 2 * qt) {  // diagonal region: causal mask
#pragma unroll
        for (int mi = 0; mi < 2; ++mi)
#pragma unroll
          for (int t = 0; t < 4; ++t)
#pragma unroll
            for (int r = 0; r < 4; ++r) {
              const int qg = q0 + mi * 16 + (ln >> 4) * 4 + r;
              const int kg = kt * 64 + t * 16 + (ln & 15);
              if (kg > qg) sc[mi][t][r] = -1e30f;
            }
      }
    }
    __syncthreads();  // all K reads done; P may overwrite K region

    // ---- online softmax (fp32, DPP row-reduce) + write P to LDS ----
    if (!skip) {
#pragma unroll
      for (int mi = 0; mi < 2; ++mi)
#pragma unroll
        for (int r = 0; r < 4; ++r) {
          float rm = fmaxf(fmaxf(sc[mi][0][r], sc[mi][1][r]),
                           fmaxf(sc[mi][2][r], sc[mi][3][r]));
          rm = rmax16(rm);
          const float mn = fmaxf(m_run[mi][r], rm);
          const float alpha = __expf(m_run[mi][r] - mn);
          m_run[mi][r] = mn;
          const int irow = mi * 16 + (ln >> 4) * 4 + r;
          float ps = 0.f;
#pragma unroll
          for (int t = 0; t < 4; ++t) {
            const float pv = __expf(sc[mi][t][r] - mn);
            ps += pv;
            *(u16*)(PlB + wv * 4608 + irow * 144 + (t * 16 + (ln & 15)) * 2) = f2bf(pv);
          }
          ps = rsum16(ps);
          l_run[mi][r] = l_run[mi][r] * alpha + ps;
#pragma unroll
          for (int n = 0; n < 8; ++n) acc_o[mi][n][r] *= alpha;
        }
    }
    asm volatile("s_waitcnt lgkmcnt(0)" ::: "memory");
    __builtin_amdgcn_sched_barrier(0);

    // ---- PV: O += P * V ----
    if (!skip) {
      short8 pf[2][2];
#pragma unroll
      for (int mi = 0; mi < 2; ++mi)
#pragma unroll
        for (int c2 = 0; c2 < 2; ++c2)
          pf[mi][c2] = *(const short8*)(PlB + wv * 4608 + (mi * 16 + (ln & 15)) * 144 +
                                        c2 * 64 + (ln >> 4) * 16);
#pragma unroll
      for (int n = 0; n < 8; ++n)
#pragma unroll
        for (int c2 = 0; c2 < 2; ++c2) {
          const int d = n * 16 + (ln & 15);
          const short8 v8 = *(const short8*)(VtB + d * 144 +
                              ((c2 * 64 + (ln >> 4) * 16) ^ (((d >> 3) & 7) << 4)));
          acc_o[0][n] = MFMA(pf[0][c2], v8, acc_o[0][n]);
          acc_o[1][n] = MFMA(pf[1][c2], v8, acc_o[1][n]);
        }
    }
    __syncthreads();
  }

  // ---- epilogue: normalize and write ctx (B,S,E) bf16 ----
  const int b = bh >> 4, h = bh & 15;
#pragma unroll
  for (int mi = 0; mi < 2; ++mi)
#pragma unroll
    for (int r = 0; r < 4; ++r) {
      const float inv = 1.f / l_run[mi][r];
      const int s = q0 + mi * 16 + (ln >> 4) * 4 + r;
#pragma unroll
      for (int n = 0; n < 8; ++n) {
        const int col = n * 16 + (ln & 15);
        ctx[((size_t)b * Sd + s) * Ed + h * Dd + col] = f2bf(acc_o[mi][n][r] * inv);
      }
    }
}

// ---------------- output projection: out[m,f] = sum_e ctx[m,e] Wo[f,e] + bo[f] ----------------
__global__ __launch_bounds__(256, 2) void k_proj(
    const u16* __restrict__ Am, const u16* __restrict__ Bm,
    const float* __restrict__ bias, float* __restrict__ out) {
  __shared__ __align__(16) u16 Ah[128*64];
  __shared__ __align__(16) u16 Bh[128*64];
  const int n0 = blockIdx.x * 128, m0 = blockIdx.y * 128;
  const int tid = threadIdx.x, wv = tid >> 6, ln = tid & 63;
  const int wm = wv >> 1, wn = wv & 1;
  const f32x4 fz = {0.f, 0.f, 0.f, 0.f};
  f32x4 acc[4][4];
#pragma unroll
  for (int m = 0; m < 4; ++m)
#pragma unroll
    for (int n = 0; n < 4; ++n) acc[m][n] = fz;

  for (int k0 = 0; k0 < Ed; k0 += 64) {
#pragma unroll
    for (int i = 0; i < 4; ++i) {
      const int lin = i * 4096 + wv * 1024 + ln * 16;
      const int row = lin >> 7;
      const int cb = lin & 127;
      const int gc = cb ^ ((row & 7) << 4);
      const int lb = i * 4096 + wv * 1024;
      gll16((const char*)Am + (size_t)(m0 + row) * (Ed * 2) + (size_t)k0 * 2 + gc, (char*)Ah + lb);
      gll16((const char*)Bm + (size_t)(n0 + row) * (Ed * 2) + (size_t)k0 * 2 + gc, (char*)Bh + lb);
    }
    __syncthreads();
#pragma unroll
    for (int kk = 0; kk < 2; ++kk) {
      short8 av[4], bv[4];
#pragma unroll
      for (int m = 0; m < 4; ++m) {
        const int row = wm * 64 + m * 16 + (ln & 15);
        const int cb = (kk * 64 + (ln >> 4) * 16) ^ ((row & 7) << 4);
        av[m] = *(const short8*)((const char*)Ah + row * 128 + cb);
      }
#pragma unroll
      for (int n = 0; n < 4; ++n) {
        const int row = wn * 64 + n * 16 + (ln & 15);
        const int cb = (kk * 64 + (ln >> 4) * 16) ^ ((row & 7) << 4);
        bv[n] = *(const short8*)((const char*)Bh + row * 128 + cb);
      }
#pragma unroll
      for (int m = 0; m < 4; ++m)
#pragma unroll
        for (int n = 0; n < 4; ++n)
          acc[m][n] = MFMA(av[m], bv[n], acc[m][n]);
    }
    __syncthreads();
  }
#pragma unroll
  for (int m = 0; m < 4; ++m)
#pragma unroll
    for (int n = 0; n < 4; ++n) {
      const int f = n0 + wn * 64 + n * 16 + (ln & 15);
      const float bi = bias[f];
#pragma unroll
      for (int r = 0; r < 4; ++r) {
        const int mg = m0 + wm * 64 + m * 16 + (ln >> 4) * 4 + r;
        out[(size_t)mg * Ed + f] = acc[m][n][r] + bi;
      }
    }
}

extern "C" void kernel_launch(void* const* d_in, const int* in_sizes, int n_in,
                              void* d_out, int out_size, void* d_ws, size_t ws_size,
                              hipStream_t stream) {
  (void)in_sizes; (void)n_in; (void)out_size; (void)ws_size;
  const float* x  = (const float*)d_in[0];
  const float* Wq = (const float*)d_in[1];
  const float* Wk = (const float*)d_in[2];
  const float* Wv = (const float*)d_in[3];
  const float* Wo = (const float*)d_in[4];
  const float* bo = (const float*)d_in[5];
  float* out = (float*)d_out;

  const size_t NTOK = (size_t)Bd * Sd * Ed;  // 8388608 elements
  const size_t NW   = (size_t)Ed * Ed;       // 4194304 elements

  char* w = (char*)d_ws;
  u16* xh = (u16*)w;  w += NTOK * 2;
  u16* xl = (u16*)w;  w += NTOK * 2;
  u16* wh = (u16*)w;  w += 3 * NW * 2;
  u16* wl = (u16*)w;  w += 3 * NW * 2;
  u16* wob = (u16*)w; w += NW * 2;
  u16* Qh = (u16*)w;  w += NTOK * 2;
  u16* Ql = (u16*)w;  w += NTOK * 2;
  u16* Kh = (u16*)w;  w += NTOK * 2;
  u16* Kl = (u16*)w;  w += NTOK * 2;
  u16* Vb = (u16*)w;  w += NTOK * 2;
  u16* ctx = (u16*)w; w += NTOK * 2;
  // total ws usage: ~193 MB

  k_split<<<dim3(2048), 256, 0, stream>>>(x, xh, xl, (int)(NTOK / 4));
  k_split<<<dim3(1024), 256, 0, stream>>>(Wq, wh, wl, (int)(NW / 4));
  k_split<<<dim3(1024), 256, 0, stream>>>(Wk, wh + NW, wl + NW, (int)(NW / 4));
  k_split<<<dim3(1024), 256, 0, stream>>>(Wv, wh + 2 * NW, wl + 2 * NW, (int)(NW / 4));
  k_cvt<<<dim3(1024), 256, 0, stream>>>(Wo, wob, (int)(NW / 4));

  k_qkv<<<dim3(Ed / 128, (Bd * Sd) / 128, 3), 256, 0, stream>>>(
      xh, xl, wh, wl, Qh, Ql, Kh, Kl, Vb);

  k_attn<<<dim3(Bd * Hd, Sd / 128), 256, 0, stream>>>(Qh, Ql, Kh, Kl, Vb, ctx);

  k_proj<<<dim3(Ed / 128, (Bd * Sd) / 128), 256, 0, stream>>>(ctx, wob, bo, out);
}

// Round 2
// 422.777 us; speedup vs baseline: 1.0160x; 1.0160x over previous
//
#include <hip/hip_runtime.h>
#include <stdint.h>
#include <stddef.h>

#define Bd 2
#define Sd 2048
#define Ed 2048
#define Hd 16
#define Dd 128

typedef unsigned short u16;
typedef __attribute__((ext_vector_type(8))) short short8;
typedef __attribute__((ext_vector_type(4))) float f32x4;

__device__ __forceinline__ u16 f2bf(float f) {
  union { float f; uint32_t u; } v; v.f = f;
  uint32_t r = v.u + 0x7FFFu + ((v.u >> 16) & 1u);
  return (u16)(r >> 16);
}
__device__ __forceinline__ float bf2f(u16 h) {
  union { uint32_t u; float f; } v; v.u = ((uint32_t)h) << 16;
  return v.f;
}
__device__ __forceinline__ void gll16(const void* g, void* lds) {
  __builtin_amdgcn_global_load_lds(
      (const __attribute__((address_space(1))) void*)g,
      (__attribute__((address_space(3))) void*)lds, 16, 0, 0);
}
template<int C> __device__ __forceinline__ float dppmv(float x) {
  return __builtin_bit_cast(float,
      __builtin_amdgcn_update_dpp(0, __builtin_bit_cast(int, x), C, 0xF, 0xF, false));
}
__device__ __forceinline__ float rmax16(float x) {
  x = fmaxf(x, dppmv<0x121>(x)); x = fmaxf(x, dppmv<0x122>(x));
  x = fmaxf(x, dppmv<0x124>(x)); x = fmaxf(x, dppmv<0x128>(x));
  return x;
}
__device__ __forceinline__ float rsum16(float x) {
  x += dppmv<0x121>(x); x += dppmv<0x122>(x);
  x += dppmv<0x124>(x); x += dppmv<0x128>(x);
  return x;
}
#define MFMA(a,b,c) __builtin_amdgcn_mfma_f32_16x16x32_bf16((a),(b),(c),0,0,0)

#define BARRIER() do { __builtin_amdgcn_s_barrier(); __builtin_amdgcn_sched_barrier(0); } while (0)
#define LGKM0() do { asm volatile("s_waitcnt lgkmcnt(0)" ::: "memory"); __builtin_amdgcn_sched_barrier(0); } while (0)

// ---------------- pre-pass: fp32 -> bf16 hi/lo split ----------------
__global__ void k_split(const float* __restrict__ src, u16* __restrict__ hi,
                        u16* __restrict__ lo, int n4) {
  const int stride = gridDim.x * blockDim.x;
  for (int i = blockIdx.x * blockDim.x + threadIdx.x; i < n4; i += stride) {
    const float4 v = ((const float4*)src)[i];
    const u16 h0 = f2bf(v.x), h1 = f2bf(v.y), h2 = f2bf(v.z), h3 = f2bf(v.w);
    ((ushort4*)hi)[i] = make_ushort4(h0, h1, h2, h3);
    ((ushort4*)lo)[i] = make_ushort4(f2bf(v.x - bf2f(h0)), f2bf(v.y - bf2f(h1)),
                                     f2bf(v.z - bf2f(h2)), f2bf(v.w - bf2f(h3)));
  }
}
__global__ void k_cvt(const float* __restrict__ src, u16* __restrict__ dst, int n4) {
  const int stride = gridDim.x * blockDim.x;
  for (int i = blockIdx.x * blockDim.x + threadIdx.x; i < n4; i += stride) {
    const float4 v = ((const float4*)src)[i];
    ((ushort4*)dst)[i] = make_ushort4(f2bf(v.x), f2bf(v.y), f2bf(v.z), f2bf(v.w));
  }
}

// ---------------- Q & K projection: 256^2-tile 8-phase template ----------------
// Split-fp32 GEMM as dense bf16 with K' = 3*2048: [xh|xh|xl] . [Wh|Wl|Wh]^T.
// 256 blocks (z<128: Q, else K), 512 threads (8 waves, 2Mx4N), wave-tile 128x64.
// LDS 128 KiB: per buffer {A[256][64], B[256][64]} swizzled; counted vmcnt(4).
__global__ __launch_bounds__(512, 2) void gemm_qk(
    const u16* __restrict__ xh, const u16* __restrict__ xl,
    const u16* __restrict__ wqh, const u16* __restrict__ wql,
    const u16* __restrict__ wkh, const u16* __restrict__ wkl,
    u16* __restrict__ Qh, u16* __restrict__ Ql,
    u16* __restrict__ Kh, u16* __restrict__ Kl) {
  constexpr int NT = 96;  // 6144 / 64
  __shared__ __align__(16) char smem[131072];
  const int lin = blockIdx.x;
  const int z = lin >> 7;
  const int rr = lin & 127;
  const int n0 = (rr & 7) * 256;   // blockIdx%8 -> n-panel: XCD L2 locality
  const int m0 = (rr >> 3) * 256;
  const u16* wh = z ? wkh : wqh;
  const u16* wl = z ? wkl : wql;
  u16* oh = z ? Kh : Qh;
  u16* ol = z ? Kl : Ql;
  const int tid = threadIdx.x, wv = tid >> 6, ln = tid & 63;
  const int wvm = wv >> 2, wvn = wv & 3;

  // stage A-tile (4x8KB units) of K'-tile tt into buffer c (linear LDS, pre-swizzled src)
  auto stageA = [&](int tt, int c) {
    const u16* A = ((tt >> 5) == 2) ? xl : xh;
    const int kin = (tt & 31) << 6;
    char* base = smem + c * 65536 + wv * 1024;
#pragma unroll
    for (int i = 0; i < 4; ++i) {
      const int l2 = i * 8192 + wv * 1024 + ln * 16;
      const int row = l2 >> 7, cb = l2 & 127;
      const int gc = cb ^ ((row & 7) << 4);
      gll16((const char*)A + (size_t)(m0 + row) * 4096 + (size_t)kin * 2 + gc,
            base + i * 8192);
    }
  };
  // stage one 8KB B unit (i in 0..3) of tile tt into buffer c
  auto stageB1 = [&](int tt, int c, int i) {
    const u16* Bp = ((tt >> 5) == 1) ? wl : wh;
    const int kin = (tt & 31) << 6;
    const int l2 = i * 8192 + wv * 1024 + ln * 16;
    const int row = l2 >> 7, cb = l2 & 127;
    const int gc = cb ^ ((row & 7) << 4);
    gll16((const char*)Bp + (size_t)(n0 + row) * 4096 + (size_t)kin * 2 + gc,
          smem + c * 65536 + 32768 + i * 8192 + wv * 1024);
  };
  auto ldA = [&](int c, int s, short8* af) {
#pragma unroll
    for (int mm = 0; mm < 8; ++mm) {
      const int row = wvm * 128 + mm * 16 + (ln & 15);
      const int cb = (s * 64 + (ln >> 4) * 16) ^ ((row & 7) << 4);
      af[mm] = *(const short8*)(smem + c * 65536 + row * 128 + cb);
    }
  };
  auto ldB = [&](int c, int s, int p, short8* bf) {
#pragma unroll
    for (int j = 0; j < 2; ++j) {
      const int row = wvn * 64 + (p * 2 + j) * 16 + (ln & 15);
      const int cb = (s * 64 + (ln >> 4) * 16) ^ ((row & 7) << 4);
      bf[j] = *(const short8*)(smem + c * 65536 + 32768 + row * 128 + cb);
    }
  };

  const f32x4 fz = {0.f, 0.f, 0.f, 0.f};
  f32x4 acc[8][4];
#pragma unroll
  for (int mm = 0; mm < 8; ++mm)
#pragma unroll
    for (int nn = 0; nn < 4; ++nn) acc[mm][nn] = fz;

  // prologue: tile0 (A+B) + tile1 A -> 12 in flight; wait to 4 (tile1 A stays out)
  stageA(0, 0);
#pragma unroll
  for (int i = 0; i < 4; ++i) stageB1(0, 0, i);
  stageA(1, 1);
  asm volatile("s_waitcnt vmcnt(4)" ::: "memory");
  BARRIER();

  for (int t = 0; t < NT; ++t) {
    const int c = t & 1;
    const bool h1 = (t + 1 < NT), h2 = (t + 2 < NT);
    short8 af[8], bf[2];
    // ---- P(0,0): A kslot0 + B kslot0 n0n1 ; stage t+1 B units 0,1
    ldA(c, 0, af);
    ldB(c, 0, 0, bf);
    if (h1) { stageB1(t + 1, c ^ 1, 0); stageB1(t + 1, c ^ 1, 1); }
    BARRIER(); LGKM0();
    __builtin_amdgcn_s_setprio(1);
#pragma unroll
    for (int mm = 0; mm < 8; ++mm) {
      acc[mm][0] = MFMA(af[mm], bf[0], acc[mm][0]);
      acc[mm][1] = MFMA(af[mm], bf[1], acc[mm][1]);
    }
    __builtin_amdgcn_s_setprio(0);
    BARRIER();
    // ---- P(0,1): B kslot0 n2n3 ; stage t+1 B unit 2
    ldB(c, 0, 1, bf);
    if (h1) stageB1(t + 1, c ^ 1, 2);
    BARRIER(); LGKM0();
    __builtin_amdgcn_s_setprio(1);
#pragma unroll
    for (int mm = 0; mm < 8; ++mm) {
      acc[mm][2] = MFMA(af[mm], bf[0], acc[mm][2]);
      acc[mm][3] = MFMA(af[mm], bf[1], acc[mm][3]);
    }
    __builtin_amdgcn_s_setprio(0);
    BARRIER();
    // ---- P(1,0): A kslot1 + B kslot1 n0n1 ; stage t+1 B unit 3
    ldA(c, 1, af);
    ldB(c, 1, 0, bf);
    if (h1) stageB1(t + 1, c ^ 1, 3);
    BARRIER(); LGKM0();
    __builtin_amdgcn_s_setprio(1);
#pragma unroll
    for (int mm = 0; mm < 8; ++mm) {
      acc[mm][0] = MFMA(af[mm], bf[0], acc[mm][0]);
      acc[mm][1] = MFMA(af[mm], bf[1], acc[mm][1]);
    }
    __builtin_amdgcn_s_setprio(0);
    BARRIER();
    // ---- P(1,1): B kslot1 n2n3 ; stage t+2 A (into just-freed A region of buf c)
    ldB(c, 1, 1, bf);
    if (h2) stageA(t + 2, c);
    BARRIER(); LGKM0();
    __builtin_amdgcn_s_setprio(1);
#pragma unroll
    for (int mm = 0; mm < 8; ++mm) {
      acc[mm][2] = MFMA(af[mm], bf[0], acc[mm][2]);
      acc[mm][3] = MFMA(af[mm], bf[1], acc[mm][3]);
    }
    __builtin_amdgcn_s_setprio(0);
    if (h2)      { asm volatile("s_waitcnt vmcnt(4)" ::: "memory"); }
    else if (h1) { asm volatile("s_waitcnt vmcnt(0)" ::: "memory"); }
    BARRIER();
  }

  // epilogue: re-split to hi/lo bf16 at (B,H,S,D)
#pragma unroll
  for (int mm = 0; mm < 8; ++mm)
#pragma unroll
    for (int nn = 0; nn < 4; ++nn)
#pragma unroll
      for (int r4 = 0; r4 < 4; ++r4) {
        const int mg = m0 + wvm * 128 + mm * 16 + (ln >> 4) * 4 + r4;
        const int f = n0 + wvn * 64 + nn * 16 + (ln & 15);
        const int b = mg >> 11, s = mg & (Sd - 1);
        const int h = f >> 7, d = f & (Dd - 1);
        const size_t o = (((size_t)b * Hd + h) * Sd + s) * Dd + d;
        const float v = acc[mm][nn][r4];
        const u16 hh = f2bf(v);
        oh[o] = hh; ol[o] = f2bf(v - bf2f(hh));
      }
}

// ---------------- V projection: 128^2 tile, single-pass bf16 ----------------
__global__ __launch_bounds__(256, 4) void k_v(
    const u16* __restrict__ xh, const u16* __restrict__ wvh,
    u16* __restrict__ Vb) {
  __shared__ __align__(16) u16 Ah[128 * 64];
  __shared__ __align__(16) u16 Bh[128 * 64];
  const int n0 = blockIdx.x * 128, m0 = blockIdx.y * 128;
  const int tid = threadIdx.x, wv = tid >> 6, ln = tid & 63;
  const int wm = wv >> 1, wn = wv & 1;
  const f32x4 fz = {0.f, 0.f, 0.f, 0.f};
  f32x4 acc[4][4];
#pragma unroll
  for (int m = 0; m < 4; ++m)
#pragma unroll
    for (int n = 0; n < 4; ++n) acc[m][n] = fz;

  for (int k0 = 0; k0 < Ed; k0 += 64) {
#pragma unroll
    for (int i = 0; i < 4; ++i) {
      const int lin = i * 4096 + wv * 1024 + ln * 16;
      const int row = lin >> 7;
      const int cb = lin & 127;
      const int gc = cb ^ ((row & 7) << 4);
      const int lb = i * 4096 + wv * 1024;
      gll16((const char*)xh + (size_t)(m0 + row) * 4096 + (size_t)k0 * 2 + gc, (char*)Ah + lb);
      gll16((const char*)wvh + (size_t)(n0 + row) * 4096 + (size_t)k0 * 2 + gc, (char*)Bh + lb);
    }
    __syncthreads();
#pragma unroll
    for (int kk = 0; kk < 2; ++kk) {
      short8 av[4], bv[4];
#pragma unroll
      for (int m = 0; m < 4; ++m) {
        const int row = wm * 64 + m * 16 + (ln & 15);
        const int cb = (kk * 64 + (ln >> 4) * 16) ^ ((row & 7) << 4);
        av[m] = *(const short8*)((const char*)Ah + row * 128 + cb);
      }
#pragma unroll
      for (int n = 0; n < 4; ++n) {
        const int row = wn * 64 + n * 16 + (ln & 15);
        const int cb = (kk * 64 + (ln >> 4) * 16) ^ ((row & 7) << 4);
        bv[n] = *(const short8*)((const char*)Bh + row * 128 + cb);
      }
#pragma unroll
      for (int m = 0; m < 4; ++m)
#pragma unroll
        for (int n = 0; n < 4; ++n)
          acc[m][n] = MFMA(av[m], bv[n], acc[m][n]);
    }
    __syncthreads();
  }
#pragma unroll
  for (int m = 0; m < 4; ++m)
#pragma unroll
    for (int n = 0; n < 4; ++n)
#pragma unroll
      for (int r = 0; r < 4; ++r) {
        const int mg = m0 + wm * 64 + m * 16 + (ln >> 4) * 4 + r;
        const int f = n0 + wn * 64 + n * 16 + (ln & 15);
        const int b = mg >> 11, s = mg & (Sd - 1);
        const int h = f >> 7, d = f & (Dd - 1);
        Vb[(((size_t)b * Hd + h) * Sd + s) * Dd + d] = f2bf(acc[m][n][r]);
      }
}

// ---------------- causal flash attention (no 1/sqrt(d) scale) ----------------
__global__ __launch_bounds__(256, 2) void k_attn(
    const u16* __restrict__ Qh, const u16* __restrict__ Ql,
    const u16* __restrict__ Kh, const u16* __restrict__ Kl,
    const u16* __restrict__ Vb, u16* __restrict__ ctx) {
  __shared__ __align__(16) char smem[51200];
  char* KhsB = smem;             // 16384 B  [64][128] bf16, swizzled
  char* KlsB = smem + 16384;     // 16384 B
  char* VtB  = smem + 32768;     // 18432 B  [128 d][72 k] bf16, swizzled
  char* PlB  = smem;             // 18432 B, ALIASES K region (barrier-separated)

  const int bh = blockIdx.x;                       // b*H + h
  const int qt = (int)gridDim.y - 1 - blockIdx.y;  // heavy tiles dispatched first
  const int tid = threadIdx.x, wv = tid >> 6, ln = tid & 63;
  const int q0 = qt * 128 + wv * 32;
  const size_t headoff = (size_t)bh * Sd * Dd;

  short8 qfh[2][4], qfl[2][4];
#pragma unroll
  for (int mi = 0; mi < 2; ++mi)
#pragma unroll
    for (int c = 0; c < 4; ++c) {
      const size_t off = headoff + (size_t)(q0 + mi * 16 + (ln & 15)) * Dd + c * 32 + (ln >> 4) * 8;
      qfh[mi][c] = *(const short8*)(Qh + off);
      qfl[mi][c] = *(const short8*)(Ql + off);
    }

  const f32x4 fz = {0.f, 0.f, 0.f, 0.f};
  f32x4 acc_o[2][8];
  float m_run[2][4], l_run[2][4];
#pragma unroll
  for (int mi = 0; mi < 2; ++mi) {
#pragma unroll
    for (int n = 0; n < 8; ++n) acc_o[mi][n] = fz;
#pragma unroll
    for (int r = 0; r < 4; ++r) { m_run[mi][r] = -1e30f; l_run[mi][r] = 0.f; }
  }

  const int ktmax = 2 * qt + 1;
  for (int kt = 0; kt <= ktmax; ++kt) {
    const size_t ktile = (headoff + (size_t)kt * 64 * Dd) * 2;
#pragma unroll
    for (int i = 0; i < 4; ++i) {
      const int lin = i * 4096 + wv * 1024 + ln * 16;
      const int row = lin >> 8;
      const int cb = lin & 255;
      const int gc = cb ^ ((row & 7) << 4);
      const size_t go = ktile + (size_t)row * 256 + gc;
      const int lb = i * 4096 + wv * 1024;
      gll16((const char*)Kh + go, KhsB + lb);
      gll16((const char*)Kl + go, KlsB + lb);
    }
#pragma unroll
    for (int p = 0; p < 4; ++p) {
      const int rr = (tid >> 4) + 16 * p;
      const int d0 = (tid & 15) * 8;
      const short8 vv = *(const short8*)(Vb + headoff + (size_t)(kt * 64 + rr) * Dd + d0);
#pragma unroll
      for (int j = 0; j < 8; ++j) {
        const int d = d0 + j;
        *(u16*)(VtB + d * 144 + ((rr * 2) ^ (((d >> 3) & 7) << 4))) = (u16)vv[j];
      }
    }
    __syncthreads();

    const bool skip = (kt * 64) > (q0 + 31);

    f32x4 sc[2][4];
#pragma unroll
    for (int mi = 0; mi < 2; ++mi)
#pragma unroll
      for (int t = 0; t < 4; ++t) sc[mi][t] = fz;
    if (!skip) {
#pragma unroll
      for (int t = 0; t < 4; ++t)
#pragma unroll
        for (int c = 0; c < 4; ++c) {
          const int row = t * 16 + (ln & 15);
          const int cb = (c * 64 + (ln >> 4) * 16) ^ ((row & 7) << 4);
          const short8 kh8 = *(const short8*)(KhsB + row * 256 + cb);
          const short8 kl8 = *(const short8*)(KlsB + row * 256 + cb);
#pragma unroll
          for (int mi = 0; mi < 2; ++mi) {
            sc[mi][t] = MFMA(qfh[mi][c], kh8, sc[mi][t]);
            sc[mi][t] = MFMA(qfh[mi][c], kl8, sc[mi][t]);
            sc[mi][t] = MFMA(qfl[mi][c], kh8, sc[mi][t]);
          }
        }
      if (kt >= 2 * qt) {
#pragma unroll
        for (int mi = 0; mi < 2; ++mi)
#pragma unroll
          for (int t = 0; t < 4; ++t)
#pragma unroll
            for (int r = 0; r < 4; ++r) {
              const int qg = q0 + mi * 16 + (ln >> 4) * 4 + r;
              const int kg = kt * 64 + t * 16 + (ln & 15);
              if (kg > qg) sc[mi][t][r] = -1e30f;
            }
      }
    }
    __syncthreads();

    if (!skip) {
#pragma unroll
      for (int mi = 0; mi < 2; ++mi)
#pragma unroll
        for (int r = 0; r < 4; ++r) {
          float rm = fmaxf(fmaxf(sc[mi][0][r], sc[mi][1][r]),
                           fmaxf(sc[mi][2][r], sc[mi][3][r]));
          rm = rmax16(rm);
          const float mn = fmaxf(m_run[mi][r], rm);
          const float alpha = __expf(m_run[mi][r] - mn);
          m_run[mi][r] = mn;
          const int irow = mi * 16 + (ln >> 4) * 4 + r;
          float ps = 0.f;
#pragma unroll
          for (int t = 0; t < 4; ++t) {
            const float pv = __expf(sc[mi][t][r] - mn);
            ps += pv;
            *(u16*)(PlB + wv * 4608 + irow * 144 + (t * 16 + (ln & 15)) * 2) = f2bf(pv);
          }
          ps = rsum16(ps);
          l_run[mi][r] = l_run[mi][r] * alpha + ps;
#pragma unroll
          for (int n = 0; n < 8; ++n) acc_o[mi][n][r] *= alpha;
        }
    }
    asm volatile("s_waitcnt lgkmcnt(0)" ::: "memory");
    __builtin_amdgcn_sched_barrier(0);

    if (!skip) {
      short8 pf[2][2];
#pragma unroll
      for (int mi = 0; mi < 2; ++mi)
#pragma unroll
        for (int c2 = 0; c2 < 2; ++c2)
          pf[mi][c2] = *(const short8*)(PlB + wv * 4608 + (mi * 16 + (ln & 15)) * 144 +
                                        c2 * 64 + (ln >> 4) * 16);
#pragma unroll
      for (int n = 0; n < 8; ++n)
#pragma unroll
        for (int c2 = 0; c2 < 2; ++c2) {
          const int d = n * 16 + (ln & 15);
          const short8 v8 = *(const short8*)(VtB + d * 144 +
                              ((c2 * 64 + (ln >> 4) * 16) ^ (((d >> 3) & 7) << 4)));
          acc_o[0][n] = MFMA(pf[0][c2], v8, acc_o[0][n]);
          acc_o[1][n] = MFMA(pf[1][c2], v8, acc_o[1][n]);
        }
    }
    __syncthreads();
  }

  const int b = bh >> 4, h = bh & 15;
#pragma unroll
  for (int mi = 0; mi < 2; ++mi)
#pragma unroll
    for (int r = 0; r < 4; ++r) {
      const float inv = 1.f / l_run[mi][r];
      const int s = q0 + mi * 16 + (ln >> 4) * 4 + r;
#pragma unroll
      for (int n = 0; n < 8; ++n) {
        const int col = n * 16 + (ln & 15);
        ctx[((size_t)b * Sd + s) * Ed + h * Dd + col] = f2bf(acc_o[mi][n][r] * inv);
      }
    }
}

// ---------------- output projection ----------------
__global__ __launch_bounds__(256, 2) void k_proj(
    const u16* __restrict__ Am, const u16* __restrict__ Bm,
    const float* __restrict__ bias, float* __restrict__ out) {
  __shared__ __align__(16) u16 Ah[128 * 64];
  __shared__ __align__(16) u16 Bh[128 * 64];
  const int n0 = blockIdx.x * 128, m0 = blockIdx.y * 128;
  const int tid = threadIdx.x, wv = tid >> 6, ln = tid & 63;
  const int wm = wv >> 1, wn = wv & 1;
  const f32x4 fz = {0.f, 0.f, 0.f, 0.f};
  f32x4 acc[4][4];
#pragma unroll
  for (int m = 0; m < 4; ++m)
#pragma unroll
    for (int n = 0; n < 4; ++n) acc[m][n] = fz;

  for (int k0 = 0; k0 < Ed; k0 += 64) {
#pragma unroll
    for (int i = 0; i < 4; ++i) {
      const int lin = i * 4096 + wv * 1024 + ln * 16;
      const int row = lin >> 7;
      const int cb = lin & 127;
      const int gc = cb ^ ((row & 7) << 4);
      const int lb = i * 4096 + wv * 1024;
      gll16((const char*)Am + (size_t)(m0 + row) * 4096 + (size_t)k0 * 2 + gc, (char*)Ah + lb);
      gll16((const char*)Bm + (size_t)(n0 + row) * 4096 + (size_t)k0 * 2 + gc, (char*)Bh + lb);
    }
    __syncthreads();
#pragma unroll
    for (int kk = 0; kk < 2; ++kk) {
      short8 av[4], bv[4];
#pragma unroll
      for (int m = 0; m < 4; ++m) {
        const int row = wm * 64 + m * 16 + (ln & 15);
        const int cb = (kk * 64 + (ln >> 4) * 16) ^ ((row & 7) << 4);
        av[m] = *(const short8*)((const char*)Ah + row * 128 + cb);
      }
#pragma unroll
      for (int n = 0; n < 4; ++n) {
        const int row = wn * 64 + n * 16 + (ln & 15);
        const int cb = (kk * 64 + (ln >> 4) * 16) ^ ((row & 7) << 4);
        bv[n] = *(const short8*)((const char*)Bh + row * 128 + cb);
      }
#pragma unroll
      for (int m = 0; m < 4; ++m)
#pragma unroll
        for (int n = 0; n < 4; ++n)
          acc[m][n] = MFMA(av[m], bv[n], acc[m][n]);
    }
    __syncthreads();
  }
#pragma unroll
  for (int m = 0; m < 4; ++m)
#pragma unroll
    for (int n = 0; n < 4; ++n) {
      const int f = n0 + wn * 64 + n * 16 + (ln & 15);
      const float bi = bias[f];
#pragma unroll
      for (int r = 0; r < 4; ++r) {
        const int mg = m0 + wm * 64 + m * 16 + (ln >> 4) * 4 + r;
        out[(size_t)mg * Ed + f] = acc[m][n][r] + bi;
      }
    }
}

extern "C" void kernel_launch(void* const* d_in, const int* in_sizes, int n_in,
                              void* d_out, int out_size, void* d_ws, size_t ws_size,
                              hipStream_t stream) {
  (void)in_sizes; (void)n_in; (void)out_size; (void)ws_size;
  const float* x  = (const float*)d_in[0];
  const float* Wq = (const float*)d_in[1];
  const float* Wk = (const float*)d_in[2];
  const float* Wv = (const float*)d_in[3];
  const float* Wo = (const float*)d_in[4];
  const float* bo = (const float*)d_in[5];
  float* out = (float*)d_out;

  const size_t NTOK = (size_t)Bd * Sd * Ed;
  const size_t NW   = (size_t)Ed * Ed;

  char* w = (char*)d_ws;
  u16* xh = (u16*)w;  w += NTOK * 2;
  u16* xl = (u16*)w;  w += NTOK * 2;
  u16* wh = (u16*)w;  w += 3 * NW * 2;
  u16* wl = (u16*)w;  w += 3 * NW * 2;
  u16* wob = (u16*)w; w += NW * 2;
  u16* Qh = (u16*)w;  w += NTOK * 2;
  u16* Ql = (u16*)w;  w += NTOK * 2;
  u16* Kh = (u16*)w;  w += NTOK * 2;
  u16* Kl = (u16*)w;  w += NTOK * 2;
  u16* Vb = (u16*)w;  w += NTOK * 2;
  u16* ctx = (u16*)w; w += NTOK * 2;

  k_split<<<dim3(2048), 256, 0, stream>>>(x, xh, xl, (int)(NTOK / 4));
  k_split<<<dim3(1024), 256, 0, stream>>>(Wq, wh, wl, (int)(NW / 4));
  k_split<<<dim3(1024), 256, 0, stream>>>(Wk, wh + NW, wl + NW, (int)(NW / 4));
  k_split<<<dim3(1024), 256, 0, stream>>>(Wv, wh + 2 * NW, wl + 2 * NW, (int)(NW / 4));
  k_cvt<<<dim3(1024), 256, 0, stream>>>(Wo, wob, (int)(NW / 4));

  gemm_qk<<<dim3(256), 512, 0, stream>>>(xh, xl, wh, wl, wh + NW, wl + NW,
                                         Qh, Ql, Kh, Kl);
  k_v<<<dim3(Ed / 128, (Bd * Sd) / 128), 256, 0, stream>>>(xh, wh + 2 * NW, Vb);

  k_attn<<<dim3(Bd * Hd, Sd / 128), 256, 0, stream>>>(Qh, Ql, Kh, Kl, Vb, ctx);

  k_proj<<<dim3(Ed / 128, (Bd * Sd) / 128), 256, 0, stream>>>(ctx, wob, bo, out);
}

// Round 3
// 414.358 us; speedup vs baseline: 1.0366x; 1.0203x over previous
//
#include <hip/hip_runtime.h>
#include <stdint.h>
#include <stddef.h>

#define Bd 2
#define Sd 2048
#define Ed 2048
#define Hd 16
#define Dd 128

typedef unsigned short u16;
typedef __attribute__((ext_vector_type(8))) short short8;
typedef __attribute__((ext_vector_type(4))) float f32x4;

__device__ __forceinline__ u16 f2bf(float f) {
  union { float f; uint32_t u; } v; v.f = f;
  uint32_t r = v.u + 0x7FFFu + ((v.u >> 16) & 1u);
  return (u16)(r >> 16);
}
__device__ __forceinline__ float bf2f(u16 h) {
  union { uint32_t u; float f; } v; v.u = ((uint32_t)h) << 16;
  return v.f;
}
__device__ __forceinline__ void gll16(const void* g, void* lds) {
  __builtin_amdgcn_global_load_lds(
      (const __attribute__((address_space(1))) void*)g,
      (__attribute__((address_space(3))) void*)lds, 16, 0, 0);
}
template<int C> __device__ __forceinline__ float dppmv(float x) {
  return __builtin_bit_cast(float,
      __builtin_amdgcn_update_dpp(0, __builtin_bit_cast(int, x), C, 0xF, 0xF, false));
}
__device__ __forceinline__ float rmax16(float x) {
  x = fmaxf(x, dppmv<0x121>(x)); x = fmaxf(x, dppmv<0x122>(x));
  x = fmaxf(x, dppmv<0x124>(x)); x = fmaxf(x, dppmv<0x128>(x));
  return x;
}
__device__ __forceinline__ float rsum16(float x) {
  x += dppmv<0x121>(x); x += dppmv<0x122>(x);
  x += dppmv<0x124>(x); x += dppmv<0x128>(x);
  return x;
}
#define MFMA(a,b,c) __builtin_amdgcn_mfma_f32_16x16x32_bf16((a),(b),(c),0,0,0)

#define BARRIER() do { __builtin_amdgcn_s_barrier(); __builtin_amdgcn_sched_barrier(0); } while (0)
#define LGKM(n) do { asm volatile("s_waitcnt lgkmcnt(" #n ")" ::: "memory"); __builtin_amdgcn_sched_barrier(0); } while (0)
#define VMCNT(n) do { asm volatile("s_waitcnt vmcnt(" #n ")" ::: "memory"); __builtin_amdgcn_sched_barrier(0); } while (0)

// ---------------- pre-pass: fp32 -> bf16 hi/lo split ----------------
__global__ void k_split(const float* __restrict__ src, u16* __restrict__ hi,
                        u16* __restrict__ lo, int n4) {
  const int stride = gridDim.x * blockDim.x;
  for (int i = blockIdx.x * blockDim.x + threadIdx.x; i < n4; i += stride) {
    const float4 v = ((const float4*)src)[i];
    const u16 h0 = f2bf(v.x), h1 = f2bf(v.y), h2 = f2bf(v.z), h3 = f2bf(v.w);
    ((ushort4*)hi)[i] = make_ushort4(h0, h1, h2, h3);
    ((ushort4*)lo)[i] = make_ushort4(f2bf(v.x - bf2f(h0)), f2bf(v.y - bf2f(h1)),
                                     f2bf(v.z - bf2f(h2)), f2bf(v.w - bf2f(h3)));
  }
}
__global__ void k_cvt(const float* __restrict__ src, u16* __restrict__ dst, int n4) {
  const int stride = gridDim.x * blockDim.x;
  for (int i = blockIdx.x * blockDim.x + threadIdx.x; i < n4; i += stride) {
    const float4 v = ((const float4*)src)[i];
    ((ushort4*)dst)[i] = make_ushort4(f2bf(v.x), f2bf(v.y), f2bf(v.z), f2bf(v.w));
  }
}

// ---------------- Q & K projection: 256^2-tile, deep-pipelined 4-phase ----------------
// Split-fp32 GEMM as dense bf16 with K' = 3*2048: [xh|xh|xl] . [Wh|Wl|Wh]^T.
// 256 blocks (z<128: Q, else K), 512 threads (8 waves, 2Mx4N), wave-tile 128x64.
// Schedule: B(t+1) staged wholly at P1 (3-phase cover), A(t+2) at P4 (full-tile
// cover); end-of-tile vmcnt(4). ds_reads {12,0,12,0} with counted lgkmcnt(2).
__global__ __launch_bounds__(512, 2) void gemm_qk(
    const u16* __restrict__ xh, const u16* __restrict__ xl,
    const u16* __restrict__ wqh, const u16* __restrict__ wql,
    const u16* __restrict__ wkh, const u16* __restrict__ wkl,
    u16* __restrict__ Qh, u16* __restrict__ Ql,
    u16* __restrict__ Kh, u16* __restrict__ Kl) {
  constexpr int NT = 96;  // 6144 / 64
  __shared__ __align__(16) char smem[131072];
  const int lin = blockIdx.x;
  const int z = lin >> 7;
  const int rr = lin & 127;
  const int n0 = (rr & 7) * 256;   // blockIdx%8 -> n-panel: XCD L2 locality
  const int m0 = (rr >> 3) * 256;
  const u16* wh = z ? wkh : wqh;
  const u16* wl = z ? wkl : wql;
  u16* oh = z ? Kh : Qh;
  u16* ol = z ? Kl : Ql;
  const int tid = threadIdx.x, wv = tid >> 6, ln = tid & 63;
  const int wvm = wv >> 2, wvn = wv & 3;

  auto stageA = [&](int tt, int c) {
    const u16* A = ((tt >> 5) == 2) ? xl : xh;
    const int kin = (tt & 31) << 6;
#pragma unroll
    for (int i = 0; i < 4; ++i) {
      const int l2 = i * 8192 + wv * 1024 + ln * 16;
      const int row = l2 >> 7, cb = l2 & 127;
      const int gc = cb ^ ((row & 7) << 4);
      gll16((const char*)A + (size_t)(m0 + row) * 4096 + (size_t)kin * 2 + gc,
            smem + c * 65536 + i * 8192 + wv * 1024);
    }
  };
  auto stageB = [&](int tt, int c) {
    const u16* Bp = ((tt >> 5) == 1) ? wl : wh;
    const int kin = (tt & 31) << 6;
#pragma unroll
    for (int i = 0; i < 4; ++i) {
      const int l2 = i * 8192 + wv * 1024 + ln * 16;
      const int row = l2 >> 7, cb = l2 & 127;
      const int gc = cb ^ ((row & 7) << 4);
      gll16((const char*)Bp + (size_t)(n0 + row) * 4096 + (size_t)kin * 2 + gc,
            smem + c * 65536 + 32768 + i * 8192 + wv * 1024);
    }
  };
  auto ldA = [&](int c, int s, short8* af) {
#pragma unroll
    for (int mm = 0; mm < 8; ++mm) {
      const int row = wvm * 128 + mm * 16 + (ln & 15);
      const int cb = (s * 64 + (ln >> 4) * 16) ^ ((row & 7) << 4);
      af[mm] = *(const short8*)(smem + c * 65536 + row * 128 + cb);
    }
  };
  auto ldB = [&](int c, int s, int p, short8* bf) {
#pragma unroll
    for (int j = 0; j < 2; ++j) {
      const int row = wvn * 64 + (p * 2 + j) * 16 + (ln & 15);
      const int cb = (s * 64 + (ln >> 4) * 16) ^ ((row & 7) << 4);
      bf[j] = *(const short8*)(smem + c * 65536 + 32768 + row * 128 + cb);
    }
  };

  const f32x4 fz = {0.f, 0.f, 0.f, 0.f};
  f32x4 acc[8][4];
#pragma unroll
  for (int mm = 0; mm < 8; ++mm)
#pragma unroll
    for (int nn = 0; nn < 4; ++nn) acc[mm][nn] = fz;

  // prologue: tile0 A+B, tile1 A -> 12 in flight; wait tile0 landed (leave 4)
  stageA(0, 0);
  stageB(0, 0);
  stageA(1, 1);
  VMCNT(4);
  BARRIER();

  for (int t = 0; t < NT; ++t) {
    const int c = t & 1;
    const bool h1 = (t + 1 < NT), h2 = (t + 2 < NT);
    short8 af[8], bf01[2], bf23[2];
    // ---- P1: ds A(k0)+B(k0,both halves); stage ALL of t+1's B
    ldA(c, 0, af);
    ldB(c, 0, 0, bf01);
    ldB(c, 0, 1, bf23);
    if (h1) stageB(t + 1, c ^ 1);
    BARRIER();
    LGKM(2);  // af+bf01 landed; bf23 lands under MFMA
    __builtin_amdgcn_s_setprio(1);
#pragma unroll
    for (int mm = 0; mm < 8; ++mm) {
      acc[mm][0] = MFMA(af[mm], bf01[0], acc[mm][0]);
      acc[mm][1] = MFMA(af[mm], bf01[1], acc[mm][1]);
    }
    __builtin_amdgcn_s_setprio(0);
    BARRIER();
    // ---- P2: no ds
    LGKM(0);
    __builtin_amdgcn_s_setprio(1);
#pragma unroll
    for (int mm = 0; mm < 8; ++mm) {
      acc[mm][2] = MFMA(af[mm], bf23[0], acc[mm][2]);
      acc[mm][3] = MFMA(af[mm], bf23[1], acc[mm][3]);
    }
    __builtin_amdgcn_s_setprio(0);
    BARRIER();
    // ---- P3: ds A(k1)+B(k1,both halves)
    ldA(c, 1, af);
    ldB(c, 1, 0, bf01);
    ldB(c, 1, 1, bf23);
    BARRIER();
    LGKM(2);
    __builtin_amdgcn_s_setprio(1);
#pragma unroll
    for (int mm = 0; mm < 8; ++mm) {
      acc[mm][0] = MFMA(af[mm], bf01[0], acc[mm][0]);
      acc[mm][1] = MFMA(af[mm], bf01[1], acc[mm][1]);
    }
    __builtin_amdgcn_s_setprio(0);
    BARRIER();
    // ---- P4: stage t+2's A into just-freed A region of buf c
    if (h2) stageA(t + 2, c);
    LGKM(0);
    __builtin_amdgcn_s_setprio(1);
#pragma unroll
    for (int mm = 0; mm < 8; ++mm) {
      acc[mm][2] = MFMA(af[mm], bf23[0], acc[mm][2]);
      acc[mm][3] = MFMA(af[mm], bf23[1], acc[mm][3]);
    }
    __builtin_amdgcn_s_setprio(0);
    if (h2)      { VMCNT(4); }
    else if (h1) { VMCNT(0); }
    BARRIER();
  }

  // epilogue: re-split to hi/lo bf16 at (B,H,S,D)
#pragma unroll
  for (int mm = 0; mm < 8; ++mm)
#pragma unroll
    for (int nn = 0; nn < 4; ++nn)
#pragma unroll
      for (int r4 = 0; r4 < 4; ++r4) {
        const int mg = m0 + wvm * 128 + mm * 16 + (ln >> 4) * 4 + r4;
        const int f = n0 + wvn * 64 + nn * 16 + (ln & 15);
        const int b = mg >> 11, s = mg & (Sd - 1);
        const int h = f >> 7, d = f & (Dd - 1);
        const size_t o = (((size_t)b * Hd + h) * Sd + s) * Dd + d;
        const float v = acc[mm][nn][r4];
        const u16 hh = f2bf(v);
        oh[o] = hh; ol[o] = f2bf(v - bf2f(hh));
      }
}

// ---------------- single-pass GEMM, 128x256 tile, same pipeline ----------------
// MODE 0: V projection (A=xh, B=wvh) -> bf16 at (B,H,S,D)
// MODE 1: out projection (A=ctx, B=wob) -> fp32 [m,f] + bias
template<int MODE>
__global__ __launch_bounds__(512, 2) void gemm1(
    const u16* __restrict__ Ap, const u16* __restrict__ Bp,
    const float* __restrict__ bias, u16* __restrict__ ob, float* __restrict__ of) {
  constexpr int NT = 32;  // 2048 / 64
  __shared__ __align__(16) char smem[98304];  // [A0 16K][B0 32K][A1 16K][B1 32K]
  const int bid = blockIdx.x;
  const int n0 = (bid & 7) * 256;
  const int m0 = (bid >> 3) * 128;
  const int tid = threadIdx.x, wv = tid >> 6, ln = tid & 63;
  const int wvm = wv >> 2, wvn = wv & 3;

  auto stageA = [&](int tt, int c) {
    const int kin = tt << 6;
#pragma unroll
    for (int i = 0; i < 2; ++i) {
      const int l2 = i * 8192 + wv * 1024 + ln * 16;
      const int row = l2 >> 7, cb = l2 & 127;
      const int gc = cb ^ ((row & 7) << 4);
      gll16((const char*)Ap + (size_t)(m0 + row) * 4096 + (size_t)kin * 2 + gc,
            smem + c * 49152 + i * 8192 + wv * 1024);
    }
  };
  auto stageB = [&](int tt, int c) {
    const int kin = tt << 6;
#pragma unroll
    for (int i = 0; i < 4; ++i) {
      const int l2 = i * 8192 + wv * 1024 + ln * 16;
      const int row = l2 >> 7, cb = l2 & 127;
      const int gc = cb ^ ((row & 7) << 4);
      gll16((const char*)Bp + (size_t)(n0 + row) * 4096 + (size_t)kin * 2 + gc,
            smem + c * 49152 + 16384 + i * 8192 + wv * 1024);
    }
  };
  auto ldA = [&](int c, int s, short8* af) {
#pragma unroll
    for (int mm = 0; mm < 4; ++mm) {
      const int row = wvm * 64 + mm * 16 + (ln & 15);
      const int cb = (s * 64 + (ln >> 4) * 16) ^ ((row & 7) << 4);
      af[mm] = *(const short8*)(smem + c * 49152 + row * 128 + cb);
    }
  };
  auto ldB = [&](int c, int s, int p, short8* bf) {
#pragma unroll
    for (int j = 0; j < 2; ++j) {
      const int row = wvn * 64 + (p * 2 + j) * 16 + (ln & 15);
      const int cb = (s * 64 + (ln >> 4) * 16) ^ ((row & 7) << 4);
      bf[j] = *(const short8*)(smem + c * 49152 + 16384 + row * 128 + cb);
    }
  };

  const f32x4 fz = {0.f, 0.f, 0.f, 0.f};
  f32x4 acc[4][4];
#pragma unroll
  for (int mm = 0; mm < 4; ++mm)
#pragma unroll
    for (int nn = 0; nn < 4; ++nn) acc[mm][nn] = fz;

  stageA(0, 0);
  stageB(0, 0);
  stageA(1, 1);
  VMCNT(2);
  BARRIER();

  for (int t = 0; t < NT; ++t) {
    const int c = t & 1;
    const bool h1 = (t + 1 < NT), h2 = (t + 2 < NT);
    short8 af[4], bf01[2], bf23[2];
    ldA(c, 0, af);
    ldB(c, 0, 0, bf01);
    ldB(c, 0, 1, bf23);
    if (h1) stageB(t + 1, c ^ 1);
    BARRIER();
    LGKM(2);
    __builtin_amdgcn_s_setprio(1);
#pragma unroll
    for (int mm = 0; mm < 4; ++mm) {
      acc[mm][0] = MFMA(af[mm], bf01[0], acc[mm][0]);
      acc[mm][1] = MFMA(af[mm], bf01[1], acc[mm][1]);
    }
    __builtin_amdgcn_s_setprio(0);
    BARRIER();
    LGKM(0);
    __builtin_amdgcn_s_setprio(1);
#pragma unroll
    for (int mm = 0; mm < 4; ++mm) {
      acc[mm][2] = MFMA(af[mm], bf23[0], acc[mm][2]);
      acc[mm][3] = MFMA(af[mm], bf23[1], acc[mm][3]);
    }
    __builtin_amdgcn_s_setprio(0);
    BARRIER();
    ldA(c, 1, af);
    ldB(c, 1, 0, bf01);
    ldB(c, 1, 1, bf23);
    BARRIER();
    LGKM(2);
    __builtin_amdgcn_s_setprio(1);
#pragma unroll
    for (int mm = 0; mm < 4; ++mm) {
      acc[mm][0] = MFMA(af[mm], bf01[0], acc[mm][0]);
      acc[mm][1] = MFMA(af[mm], bf01[1], acc[mm][1]);
    }
    __builtin_amdgcn_s_setprio(0);
    BARRIER();
    if (h2) stageA(t + 2, c);
    LGKM(0);
    __builtin_amdgcn_s_setprio(1);
#pragma unroll
    for (int mm = 0; mm < 4; ++mm) {
      acc[mm][2] = MFMA(af[mm], bf23[0], acc[mm][2]);
      acc[mm][3] = MFMA(af[mm], bf23[1], acc[mm][3]);
    }
    __builtin_amdgcn_s_setprio(0);
    if (h2)      { VMCNT(2); }
    else if (h1) { VMCNT(0); }
    BARRIER();
  }

#pragma unroll
  for (int mm = 0; mm < 4; ++mm)
#pragma unroll
    for (int nn = 0; nn < 4; ++nn) {
      const int f = n0 + wvn * 64 + nn * 16 + (ln & 15);
      float bi = 0.f;
      if (MODE == 1) bi = bias[f];
#pragma unroll
      for (int r4 = 0; r4 < 4; ++r4) {
        const int mg = m0 + wvm * 64 + mm * 16 + (ln >> 4) * 4 + r4;
        if (MODE == 0) {
          const int b = mg >> 11, s = mg & (Sd - 1);
          const int h = f >> 7, d = f & (Dd - 1);
          ob[(((size_t)b * Hd + h) * Sd + s) * Dd + d] = f2bf(acc[mm][nn][r4]);
        } else {
          of[(size_t)mg * Ed + f] = acc[mm][nn][r4] + bi;
        }
      }
    }
}

// ---------------- causal flash attention (no 1/sqrt(d) scale) ----------------
__global__ __launch_bounds__(256, 2) void k_attn(
    const u16* __restrict__ Qh, const u16* __restrict__ Ql,
    const u16* __restrict__ Kh, const u16* __restrict__ Kl,
    const u16* __restrict__ Vb, u16* __restrict__ ctx) {
  __shared__ __align__(16) char smem[51200];
  char* KhsB = smem;             // 16384 B  [64][128] bf16, swizzled
  char* KlsB = smem + 16384;     // 16384 B
  char* VtB  = smem + 32768;     // 18432 B  [128 d][72 k] bf16, swizzled
  char* PlB  = smem;             // 18432 B, ALIASES K region (barrier-separated)

  const int bh = blockIdx.x;
  const int qt = (int)gridDim.y - 1 - blockIdx.y;
  const int tid = threadIdx.x, wv = tid >> 6, ln = tid & 63;
  const int q0 = qt * 128 + wv * 32;
  const size_t headoff = (size_t)bh * Sd * Dd;

  short8 qfh[2][4], qfl[2][4];
#pragma unroll
  for (int mi = 0; mi < 2; ++mi)
#pragma unroll
    for (int c = 0; c < 4; ++c) {
      const size_t off = headoff + (size_t)(q0 + mi * 16 + (ln & 15)) * Dd + c * 32 + (ln >> 4) * 8;
      qfh[mi][c] = *(const short8*)(Qh + off);
      qfl[mi][c] = *(const short8*)(Ql + off);
    }

  const f32x4 fz = {0.f, 0.f, 0.f, 0.f};
  f32x4 acc_o[2][8];
  float m_run[2][4], l_run[2][4];
#pragma unroll
  for (int mi = 0; mi < 2; ++mi) {
#pragma unroll
    for (int n = 0; n < 8; ++n) acc_o[mi][n] = fz;
#pragma unroll
    for (int r = 0; r < 4; ++r) { m_run[mi][r] = -1e30f; l_run[mi][r] = 0.f; }
  }

  const int ktmax = 2 * qt + 1;
  for (int kt = 0; kt <= ktmax; ++kt) {
    const size_t ktile = (headoff + (size_t)kt * 64 * Dd) * 2;
#pragma unroll
    for (int i = 0; i < 4; ++i) {
      const int lin = i * 4096 + wv * 1024 + ln * 16;
      const int row = lin >> 8;
      const int cb = lin & 255;
      const int gc = cb ^ ((row & 7) << 4);
      const size_t go = ktile + (size_t)row * 256 + gc;
      const int lb = i * 4096 + wv * 1024;
      gll16((const char*)Kh + go, KhsB + lb);
      gll16((const char*)Kl + go, KlsB + lb);
    }
#pragma unroll
    for (int p = 0; p < 4; ++p) {
      const int rr = (tid >> 4) + 16 * p;
      const int d0 = (tid & 15) * 8;
      const short8 vv = *(const short8*)(Vb + headoff + (size_t)(kt * 64 + rr) * Dd + d0);
#pragma unroll
      for (int j = 0; j < 8; ++j) {
        const int d = d0 + j;
        *(u16*)(VtB + d * 144 + ((rr * 2) ^ (((d >> 3) & 7) << 4))) = (u16)vv[j];
      }
    }
    __syncthreads();

    const bool skip = (kt * 64) > (q0 + 31);

    f32x4 sc[2][4];
#pragma unroll
    for (int mi = 0; mi < 2; ++mi)
#pragma unroll
      for (int t = 0; t < 4; ++t) sc[mi][t] = fz;
    if (!skip) {
#pragma unroll
      for (int t = 0; t < 4; ++t)
#pragma unroll
        for (int c = 0; c < 4; ++c) {
          const int row = t * 16 + (ln & 15);
          const int cb = (c * 64 + (ln >> 4) * 16) ^ ((row & 7) << 4);
          const short8 kh8 = *(const short8*)(KhsB + row * 256 + cb);
          const short8 kl8 = *(const short8*)(KlsB + row * 256 + cb);
#pragma unroll
          for (int mi = 0; mi < 2; ++mi) {
            sc[mi][t] = MFMA(qfh[mi][c], kh8, sc[mi][t]);
            sc[mi][t] = MFMA(qfh[mi][c], kl8, sc[mi][t]);
            sc[mi][t] = MFMA(qfl[mi][c], kh8, sc[mi][t]);
          }
        }
      if (kt >= 2 * qt) {
#pragma unroll
        for (int mi = 0; mi < 2; ++mi)
#pragma unroll
          for (int t = 0; t < 4; ++t)
#pragma unroll
            for (int r = 0; r < 4; ++r) {
              const int qg = q0 + mi * 16 + (ln >> 4) * 4 + r;
              const int kg = kt * 64 + t * 16 + (ln & 15);
              if (kg > qg) sc[mi][t][r] = -1e30f;
            }
      }
    }
    __syncthreads();

    if (!skip) {
#pragma unroll
      for (int mi = 0; mi < 2; ++mi)
#pragma unroll
        for (int r = 0; r < 4; ++r) {
          float rm = fmaxf(fmaxf(sc[mi][0][r], sc[mi][1][r]),
                           fmaxf(sc[mi][2][r], sc[mi][3][r]));
          rm = rmax16(rm);
          const float mn = fmaxf(m_run[mi][r], rm);
          const float alpha = __expf(m_run[mi][r] - mn);
          m_run[mi][r] = mn;
          const int irow = mi * 16 + (ln >> 4) * 4 + r;
          float ps = 0.f;
#pragma unroll
          for (int t = 0; t < 4; ++t) {
            const float pv = __expf(sc[mi][t][r] - mn);
            ps += pv;
            *(u16*)(PlB + wv * 4608 + irow * 144 + (t * 16 + (ln & 15)) * 2) = f2bf(pv);
          }
          ps = rsum16(ps);
          l_run[mi][r] = l_run[mi][r] * alpha + ps;
#pragma unroll
          for (int n = 0; n < 8; ++n) acc_o[mi][n][r] *= alpha;
        }
    }
    asm volatile("s_waitcnt lgkmcnt(0)" ::: "memory");
    __builtin_amdgcn_sched_barrier(0);

    if (!skip) {
      short8 pf[2][2];
#pragma unroll
      for (int mi = 0; mi < 2; ++mi)
#pragma unroll
        for (int c2 = 0; c2 < 2; ++c2)
          pf[mi][c2] = *(const short8*)(PlB + wv * 4608 + (mi * 16 + (ln & 15)) * 144 +
                                        c2 * 64 + (ln >> 4) * 16);
#pragma unroll
      for (int n = 0; n < 8; ++n)
#pragma unroll
        for (int c2 = 0; c2 < 2; ++c2) {
          const int d = n * 16 + (ln & 15);
          const short8 v8 = *(const short8*)(VtB + d * 144 +
                              ((c2 * 64 + (ln >> 4) * 16) ^ (((d >> 3) & 7) << 4)));
          acc_o[0][n] = MFMA(pf[0][c2], v8, acc_o[0][n]);
          acc_o[1][n] = MFMA(pf[1][c2], v8, acc_o[1][n]);
        }
    }
    __syncthreads();
  }

  const int b = bh >> 4, h = bh & 15;
#pragma unroll
  for (int mi = 0; mi < 2; ++mi)
#pragma unroll
    for (int r = 0; r < 4; ++r) {
      const float inv = 1.f / l_run[mi][r];
      const int s = q0 + mi * 16 + (ln >> 4) * 4 + r;
#pragma unroll
      for (int n = 0; n < 8; ++n) {
        const int col = n * 16 + (ln & 15);
        ctx[((size_t)b * Sd + s) * Ed + h * Dd + col] = f2bf(acc_o[mi][n][r] * inv);
      }
    }
}

extern "C" void kernel_launch(void* const* d_in, const int* in_sizes, int n_in,
                              void* d_out, int out_size, void* d_ws, size_t ws_size,
                              hipStream_t stream) {
  (void)in_sizes; (void)n_in; (void)out_size; (void)ws_size;
  const float* x  = (const float*)d_in[0];
  const float* Wq = (const float*)d_in[1];
  const float* Wk = (const float*)d_in[2];
  const float* Wv = (const float*)d_in[3];
  const float* Wo = (const float*)d_in[4];
  const float* bo = (const float*)d_in[5];
  float* out = (float*)d_out;

  const size_t NTOK = (size_t)Bd * Sd * Ed;
  const size_t NW   = (size_t)Ed * Ed;

  char* w = (char*)d_ws;
  u16* xh = (u16*)w;  w += NTOK * 2;
  u16* xl = (u16*)w;  w += NTOK * 2;
  u16* wh = (u16*)w;  w += 3 * NW * 2;
  u16* wl = (u16*)w;  w += 3 * NW * 2;
  u16* wob = (u16*)w; w += NW * 2;
  u16* Qh = (u16*)w;  w += NTOK * 2;
  u16* Ql = (u16*)w;  w += NTOK * 2;
  u16* Kh = (u16*)w;  w += NTOK * 2;
  u16* Kl = (u16*)w;  w += NTOK * 2;
  u16* Vb = (u16*)w;  w += NTOK * 2;
  u16* ctx = (u16*)w; w += NTOK * 2;

  k_split<<<dim3(2048), 256, 0, stream>>>(x, xh, xl, (int)(NTOK / 4));
  k_split<<<dim3(1024), 256, 0, stream>>>(Wq, wh, wl, (int)(NW / 4));
  k_split<<<dim3(1024), 256, 0, stream>>>(Wk, wh + NW, wl + NW, (int)(NW / 4));
  k_split<<<dim3(1024), 256, 0, stream>>>(Wv, wh + 2 * NW, wl + 2 * NW, (int)(NW / 4));
  k_cvt<<<dim3(1024), 256, 0, stream>>>(Wo, wob, (int)(NW / 4));

  gemm_qk<<<dim3(256), 512, 0, stream>>>(xh, xl, wh, wl, wh + NW, wl + NW,
                                         Qh, Ql, Kh, Kl);
  gemm1<0><<<dim3(256), 512, 0, stream>>>(xh, wh + 2 * NW, nullptr, Vb, nullptr);

  k_attn<<<dim3(Bd * Hd, Sd / 128), 256, 0, stream>>>(Qh, Ql, Kh, Kl, Vb, ctx);

  gemm1<1><<<dim3(256), 512, 0, stream>>>(ctx, wob, bo, nullptr, out);
}

// Round 4
// 412.562 us; speedup vs baseline: 1.0411x; 1.0044x over previous
//
#include <hip/hip_runtime.h>
#include <stdint.h>
#include <stddef.h>

#define Bd 2
#define Sd 2048
#define Ed 2048
#define Hd 16
#define Dd 128

typedef unsigned short u16;
typedef __attribute__((ext_vector_type(8))) short short8;
typedef __attribute__((ext_vector_type(4))) float f32x4;

__device__ __forceinline__ u16 f2bf(float f) {
  union { float f; uint32_t u; } v; v.f = f;
  uint32_t r = v.u + 0x7FFFu + ((v.u >> 16) & 1u);
  return (u16)(r >> 16);
}
__device__ __forceinline__ float bf2f(u16 h) {
  union { uint32_t u; float f; } v; v.u = ((uint32_t)h) << 16;
  return v.f;
}
__device__ __forceinline__ void gll16(const void* g, void* lds) {
  __builtin_amdgcn_global_load_lds(
      (const __attribute__((address_space(1))) void*)g,
      (__attribute__((address_space(3))) void*)lds, 16, 0, 0);
}
template<int C> __device__ __forceinline__ float dppmv(float x) {
  return __builtin_bit_cast(float,
      __builtin_amdgcn_update_dpp(0, __builtin_bit_cast(int, x), C, 0xF, 0xF, false));
}
__device__ __forceinline__ float rmax16(float x) {
  x = fmaxf(x, dppmv<0x121>(x)); x = fmaxf(x, dppmv<0x122>(x));
  x = fmaxf(x, dppmv<0x124>(x)); x = fmaxf(x, dppmv<0x128>(x));
  return x;
}
__device__ __forceinline__ float rsum16(float x) {
  x += dppmv<0x121>(x); x += dppmv<0x122>(x);
  x += dppmv<0x124>(x); x += dppmv<0x128>(x);
  return x;
}
#define MFMA(a,b,c) __builtin_amdgcn_mfma_f32_16x16x32_bf16((a),(b),(c),0,0,0)

#define BARRIER() do { __builtin_amdgcn_s_barrier(); __builtin_amdgcn_sched_barrier(0); } while (0)
#define LGKM(n) do { asm volatile("s_waitcnt lgkmcnt(" #n ")" ::: "memory"); __builtin_amdgcn_sched_barrier(0); } while (0)
#define VMCNT(n) do { asm volatile("s_waitcnt vmcnt(" #n ")" ::: "memory"); __builtin_amdgcn_sched_barrier(0); } while (0)

// ---------------- pre-pass: fp32 -> bf16 hi/lo split ----------------
__global__ void k_split(const float* __restrict__ src, u16* __restrict__ hi,
                        u16* __restrict__ lo, int n4) {
  const int stride = gridDim.x * blockDim.x;
  for (int i = blockIdx.x * blockDim.x + threadIdx.x; i < n4; i += stride) {
    const float4 v = ((const float4*)src)[i];
    const u16 h0 = f2bf(v.x), h1 = f2bf(v.y), h2 = f2bf(v.z), h3 = f2bf(v.w);
    ((ushort4*)hi)[i] = make_ushort4(h0, h1, h2, h3);
    ((ushort4*)lo)[i] = make_ushort4(f2bf(v.x - bf2f(h0)), f2bf(v.y - bf2f(h1)),
                                     f2bf(v.z - bf2f(h2)), f2bf(v.w - bf2f(h3)));
  }
}
__global__ void k_cvt(const float* __restrict__ src, u16* __restrict__ dst, int n4) {
  const int stride = gridDim.x * blockDim.x;
  for (int i = blockIdx.x * blockDim.x + threadIdx.x; i < n4; i += stride) {
    const float4 v = ((const float4*)src)[i];
    ((ushort4*)dst)[i] = make_ushort4(f2bf(v.x), f2bf(v.y), f2bf(v.z), f2bf(v.w));
  }
}

// ---------------- Q & K projection: 256^2-tile, m201 8-phase schedule ----------------
// Split-fp32 GEMM as dense bf16 with K' = 3*2048: [xh|xh|xl] . [Wh|Wl|Wh]^T.
// 256 blocks (z<128: Q, else K), 512 threads (8 waves, 2Mx4N), wave-tile 128x64.
// Per K-tile (4 phases): quadrants Q(h,n2); ds {12,4,8,0}; one 16KB stage event
// per phase matched to region last-reads; vmcnt(6) once per K-tile (tail: 0).
__global__ __launch_bounds__(512, 2) void gemm_qk(
    const u16* __restrict__ xh, const u16* __restrict__ xl,
    const u16* __restrict__ wqh, const u16* __restrict__ wql,
    const u16* __restrict__ wkh, const u16* __restrict__ wkl,
    u16* __restrict__ Qh, u16* __restrict__ Ql,
    u16* __restrict__ Kh, u16* __restrict__ Kl) {
  constexpr int NT = 96;  // 6144 / 64
  __shared__ __align__(16) char smem[131072];
  const int lin = blockIdx.x;
  const int z = lin >> 7;
  const int rr = lin & 127;
  const int n0 = (rr & 7) * 256;   // blockIdx%8 -> n-panel: XCD L2 locality
  const int m0 = (rr >> 3) * 256;
  const u16* wh = z ? wkh : wqh;
  const u16* wl = z ? wkl : wql;
  u16* oh = z ? Kh : Qh;
  u16* ol = z ? Kl : Ql;
  const int tid = threadIdx.x, wv = tid >> 6, ln = tid & 63;
  const int wvm = wv >> 2, wvn = wv & 3;

  // ---- stage events: 16KB each = 2 gll per wave (1KB chunks, 8 rows each) ----
  // A event par=0: units {0,2} (rows 0-63,128-191: read only in P1 of its K-tile)
  // A event par=1: units {1,3} (rows 64-127,192-255: read only in P3)
  auto stgA = [&](int tt, int par) {
    if (tt >= NT) return;
    const u16* A = ((tt >> 5) == 2) ? xl : xh;
    const int kin = (tt & 31) << 6;
    const int c = tt & 1;
    const int r8 = ln >> 3, cc = ((ln & 7) ^ r8) * 16;
#pragma unroll
    for (int e = 0; e < 2; ++e) {
      const int ch = e * 8 + wv;
      const int trow = (par + (ch >> 3) * 2) * 64 + (ch & 7) * 8;
      gll16((const char*)A + (size_t)(m0 + trow + r8) * 4096 + (size_t)kin * 2 + cc,
            smem + c * 65536 + trow * 128);
    }
  };
  // B event n2: 32-row stripes {s*64+n2*32 .. +32} for s=0..3 (read in P(1+n2))
  auto stgB = [&](int tt, int n2) {
    if (tt >= NT) return;
    const u16* Bp = ((tt >> 5) == 1) ? wl : wh;
    const int kin = (tt & 31) << 6;
    const int c = tt & 1;
    const int r8 = ln >> 3, cc = ((ln & 7) ^ r8) * 16;
#pragma unroll
    for (int e = 0; e < 2; ++e) {
      const int ch = e * 8 + wv;
      const int trow = (ch >> 2) * 64 + n2 * 32 + (ch & 3) * 8;
      gll16((const char*)Bp + (size_t)(n0 + trow + r8) * 4096 + (size_t)kin * 2 + cc,
            smem + c * 65536 + 32768 + trow * 128);
    }
  };
  // ---- register fragment loads (both kslots of one A-half / B-half) ----
  auto ldAh = [&](int c, int h, short8 (*a)[2]) {
#pragma unroll
    for (int mm = 0; mm < 4; ++mm) {
      const int row = wvm * 128 + h * 64 + mm * 16 + (ln & 15);
#pragma unroll
      for (int s = 0; s < 2; ++s) {
        const int cb = (s * 64 + (ln >> 4) * 16) ^ ((row & 7) << 4);
        a[mm][s] = *(const short8*)(smem + c * 65536 + row * 128 + cb);
      }
    }
  };
  auto ldBh = [&](int c, int n2, short8 (*b)[2]) {
#pragma unroll
    for (int nn = 0; nn < 2; ++nn) {
      const int row = wvn * 64 + (n2 * 2 + nn) * 16 + (ln & 15);
#pragma unroll
      for (int s = 0; s < 2; ++s) {
        const int cb = (s * 64 + (ln >> 4) * 16) ^ ((row & 7) << 4);
        b[nn][s] = *(const short8*)(smem + c * 65536 + 32768 + row * 128 + cb);
      }
    }
  };

  const f32x4 fz = {0.f, 0.f, 0.f, 0.f};
  f32x4 acc[8][4];
#pragma unroll
  for (int mm = 0; mm < 8; ++mm)
#pragma unroll
    for (int nn = 0; nn < 4; ++nn) acc[mm][nn] = fz;

#define QUAD(MB, NB, AA, BB)                                                    \
  do {                                                                          \
    __builtin_amdgcn_s_setprio(1);                                              \
    _Pragma("unroll")                                                           \
    for (int mm = 0; mm < 4; ++mm)                                              \
      _Pragma("unroll")                                                         \
      for (int nn = 0; nn < 2; ++nn) {                                          \
        acc[MB + mm][NB + nn] = MFMA(AA[mm][0], BB[nn][0], acc[MB + mm][NB + nn]); \
        acc[MB + mm][NB + nn] = MFMA(AA[mm][1], BB[nn][1], acc[MB + mm][NB + nn]); \
      }                                                                         \
    __builtin_amdgcn_s_setprio(0);                                              \
  } while (0)

  // prologue: K0 complete + K1 {A-early, B0, B1}; K1's A-late staged at w=0 P1
  stgA(0, 0); stgA(0, 1); stgB(0, 0); stgB(0, 1);
  stgA(1, 0); stgB(1, 0); stgB(1, 1);
  VMCNT(6);   // retires K0's 8 loads; K1's 6 may stay in flight
  BARRIER();

  for (int w = 0; w < NT; ++w) {
    const int c = w & 1;
    short8 a[4][2], b0[2][2], b1[2][2];
    // ---- P1: ds A(h0)+B(n2=0) [12]; stage A-late(w+1)
    ldAh(c, 0, a);
    ldBh(c, 0, b0);
    stgA(w + 1, 1);
    BARRIER(); LGKM(0);
    QUAD(0, 0, a, b0);
    BARRIER();
    // ---- P2: ds B(n2=1) [4]; stage A-early(w+2)
    ldBh(c, 1, b1);
    stgA(w + 2, 0);
    BARRIER(); LGKM(0);
    QUAD(0, 2, a, b1);
    BARRIER();
    // ---- P3: ds A(h1) [8]; stage B0(w+2)
    ldAh(c, 1, a);
    stgB(w + 2, 0);
    BARRIER(); LGKM(0);
    QUAD(4, 0, a, b0);
    BARRIER();
    // ---- P4: stage B1(w+2); counted vmcnt
    stgB(w + 2, 1);
    BARRIER();
    QUAD(4, 2, a, b1);
    if (w + 2 < NT) { VMCNT(6); } else { VMCNT(0); }
    BARRIER();
  }
#undef QUAD

  // epilogue: re-split to hi/lo bf16 at (B,H,S,D)
#pragma unroll
  for (int mm = 0; mm < 8; ++mm)
#pragma unroll
    for (int nn = 0; nn < 4; ++nn)
#pragma unroll
      for (int r4 = 0; r4 < 4; ++r4) {
        const int mg = m0 + wvm * 128 + mm * 16 + (ln >> 4) * 4 + r4;
        const int f = n0 + wvn * 64 + nn * 16 + (ln & 15);
        const int b = mg >> 11, s = mg & (Sd - 1);
        const int h = f >> 7, d = f & (Dd - 1);
        const size_t o = (((size_t)b * Hd + h) * Sd + s) * Dd + d;
        const float v = acc[mm][nn][r4];
        const u16 hh = f2bf(v);
        oh[o] = hh; ol[o] = f2bf(v - bf2f(hh));
      }
}

// ---------------- single-pass GEMM, 128x256 tile, 4-phase pipeline ----------------
// MODE 0: V projection (A=xh, B=wvh) -> bf16 at (B,H,S,D)
// MODE 1: out projection (A=ctx, B=wob) -> fp32 [m,f] + bias
template<int MODE>
__global__ __launch_bounds__(512, 2) void gemm1(
    const u16* __restrict__ Ap, const u16* __restrict__ Bp,
    const float* __restrict__ bias, u16* __restrict__ ob, float* __restrict__ of) {
  constexpr int NT = 32;  // 2048 / 64
  __shared__ __align__(16) char smem[98304];  // [A0 16K][B0 32K][A1 16K][B1 32K]
  const int bid = blockIdx.x;
  const int n0 = (bid & 7) * 256;
  const int m0 = (bid >> 3) * 128;
  const int tid = threadIdx.x, wv = tid >> 6, ln = tid & 63;
  const int wvm = wv >> 2, wvn = wv & 3;

  auto stageA = [&](int tt, int c) {
    const int kin = tt << 6;
#pragma unroll
    for (int i = 0; i < 2; ++i) {
      const int l2 = i * 8192 + wv * 1024 + ln * 16;
      const int row = l2 >> 7, cb = l2 & 127;
      const int gc = cb ^ ((row & 7) << 4);
      gll16((const char*)Ap + (size_t)(m0 + row) * 4096 + (size_t)kin * 2 + gc,
            smem + c * 49152 + i * 8192 + wv * 1024);
    }
  };
  auto stageB = [&](int tt, int c) {
    const int kin = tt << 6;
#pragma unroll
    for (int i = 0; i < 4; ++i) {
      const int l2 = i * 8192 + wv * 1024 + ln * 16;
      const int row = l2 >> 7, cb = l2 & 127;
      const int gc = cb ^ ((row & 7) << 4);
      gll16((const char*)Bp + (size_t)(n0 + row) * 4096 + (size_t)kin * 2 + gc,
            smem + c * 49152 + 16384 + i * 8192 + wv * 1024);
    }
  };
  auto ldA = [&](int c, int s, short8* af) {
#pragma unroll
    for (int mm = 0; mm < 4; ++mm) {
      const int row = wvm * 64 + mm * 16 + (ln & 15);
      const int cb = (s * 64 + (ln >> 4) * 16) ^ ((row & 7) << 4);
      af[mm] = *(const short8*)(smem + c * 49152 + row * 128 + cb);
    }
  };
  auto ldB = [&](int c, int s, int p, short8* bf) {
#pragma unroll
    for (int j = 0; j < 2; ++j) {
      const int row = wvn * 64 + (p * 2 + j) * 16 + (ln & 15);
      const int cb = (s * 64 + (ln >> 4) * 16) ^ ((row & 7) << 4);
      bf[j] = *(const short8*)(smem + c * 49152 + 16384 + row * 128 + cb);
    }
  };

  const f32x4 fz = {0.f, 0.f, 0.f, 0.f};
  f32x4 acc[4][4];
#pragma unroll
  for (int mm = 0; mm < 4; ++mm)
#pragma unroll
    for (int nn = 0; nn < 4; ++nn) acc[mm][nn] = fz;

  stageA(0, 0);
  stageB(0, 0);
  stageA(1, 1);
  VMCNT(2);
  BARRIER();

  for (int t = 0; t < NT; ++t) {
    const int c = t & 1;
    const bool h1 = (t + 1 < NT), h2 = (t + 2 < NT);
    short8 af[4], bf01[2], bf23[2];
    ldA(c, 0, af);
    ldB(c, 0, 0, bf01);
    ldB(c, 0, 1, bf23);
    if (h1) stageB(t + 1, c ^ 1);
    BARRIER();
    LGKM(2);
    __builtin_amdgcn_s_setprio(1);
#pragma unroll
    for (int mm = 0; mm < 4; ++mm) {
      acc[mm][0] = MFMA(af[mm], bf01[0], acc[mm][0]);
      acc[mm][1] = MFMA(af[mm], bf01[1], acc[mm][1]);
    }
    __builtin_amdgcn_s_setprio(0);
    BARRIER();
    LGKM(0);
    __builtin_amdgcn_s_setprio(1);
#pragma unroll
    for (int mm = 0; mm < 4; ++mm) {
      acc[mm][2] = MFMA(af[mm], bf23[0], acc[mm][2]);
      acc[mm][3] = MFMA(af[mm], bf23[1], acc[mm][3]);
    }
    __builtin_amdgcn_s_setprio(0);
    BARRIER();
    ldA(c, 1, af);
    ldB(c, 1, 0, bf01);
    ldB(c, 1, 1, bf23);
    BARRIER();
    LGKM(2);
    __builtin_amdgcn_s_setprio(1);
#pragma unroll
    for (int mm = 0; mm < 4; ++mm) {
      acc[mm][0] = MFMA(af[mm], bf01[0], acc[mm][0]);
      acc[mm][1] = MFMA(af[mm], bf01[1], acc[mm][1]);
    }
    __builtin_amdgcn_s_setprio(0);
    BARRIER();
    if (h2) stageA(t + 2, c);
    LGKM(0);
    __builtin_amdgcn_s_setprio(1);
#pragma unroll
    for (int mm = 0; mm < 4; ++mm) {
      acc[mm][2] = MFMA(af[mm], bf23[0], acc[mm][2]);
      acc[mm][3] = MFMA(af[mm], bf23[1], acc[mm][3]);
    }
    __builtin_amdgcn_s_setprio(0);
    if (h2)      { VMCNT(2); }
    else if (h1) { VMCNT(0); }
    BARRIER();
  }

#pragma unroll
  for (int mm = 0; mm < 4; ++mm)
#pragma unroll
    for (int nn = 0; nn < 4; ++nn) {
      const int f = n0 + wvn * 64 + nn * 16 + (ln & 15);
      float bi = 0.f;
      if (MODE == 1) bi = bias[f];
#pragma unroll
      for (int r4 = 0; r4 < 4; ++r4) {
        const int mg = m0 + wvm * 64 + mm * 16 + (ln >> 4) * 4 + r4;
        if (MODE == 0) {
          const int b = mg >> 11, s = mg & (Sd - 1);
          const int h = f >> 7, d = f & (Dd - 1);
          ob[(((size_t)b * Hd + h) * Sd + s) * Dd + d] = f2bf(acc[mm][nn][r4]);
        } else {
          of[(size_t)mg * Ed + f] = acc[mm][nn][r4] + bi;
        }
      }
    }
}

// ---------------- causal flash attention (no 1/sqrt(d) scale) ----------------
__global__ __launch_bounds__(256, 2) void k_attn(
    const u16* __restrict__ Qh, const u16* __restrict__ Ql,
    const u16* __restrict__ Kh, const u16* __restrict__ Kl,
    const u16* __restrict__ Vb, u16* __restrict__ ctx) {
  __shared__ __align__(16) char smem[51200];
  char* KhsB = smem;             // 16384 B  [64][128] bf16, swizzled
  char* KlsB = smem + 16384;     // 16384 B
  char* VtB  = smem + 32768;     // 18432 B  [128 d][72 k] bf16, swizzled
  char* PlB  = smem;             // 18432 B, ALIASES K region (barrier-separated)

  const int bh = blockIdx.x;
  const int qt = (int)gridDim.y - 1 - blockIdx.y;
  const int tid = threadIdx.x, wv = tid >> 6, ln = tid & 63;
  const int q0 = qt * 128 + wv * 32;
  const size_t headoff = (size_t)bh * Sd * Dd;

  short8 qfh[2][4], qfl[2][4];
#pragma unroll
  for (int mi = 0; mi < 2; ++mi)
#pragma unroll
    for (int c = 0; c < 4; ++c) {
      const size_t off = headoff + (size_t)(q0 + mi * 16 + (ln & 15)) * Dd + c * 32 + (ln >> 4) * 8;
      qfh[mi][c] = *(const short8*)(Qh + off);
      qfl[mi][c] = *(const short8*)(Ql + off);
    }

  const f32x4 fz = {0.f, 0.f, 0.f, 0.f};
  f32x4 acc_o[2][8];
  float m_run[2][4], l_run[2][4];
#pragma unroll
  for (int mi = 0; mi < 2; ++mi) {
#pragma unroll
    for (int n = 0; n < 8; ++n) acc_o[mi][n] = fz;
#pragma unroll
    for (int r = 0; r < 4; ++r) { m_run[mi][r] = -1e30f; l_run[mi][r] = 0.f; }
  }

  const int ktmax = 2 * qt + 1;
  for (int kt = 0; kt <= ktmax; ++kt) {
    const size_t ktile = (headoff + (size_t)kt * 64 * Dd) * 2;
#pragma unroll
    for (int i = 0; i < 4; ++i) {
      const int lin = i * 4096 + wv * 1024 + ln * 16;
      const int row = lin >> 8;
      const int cb = lin & 255;
      const int gc = cb ^ ((row & 7) << 4);
      const size_t go = ktile + (size_t)row * 256 + gc;
      const int lb = i * 4096 + wv * 1024;
      gll16((const char*)Kh + go, KhsB + lb);
      gll16((const char*)Kl + go, KlsB + lb);
    }
#pragma unroll
    for (int p = 0; p < 4; ++p) {
      const int rr = (tid >> 4) + 16 * p;
      const int d0 = (tid & 15) * 8;
      const short8 vv = *(const short8*)(Vb + headoff + (size_t)(kt * 64 + rr) * Dd + d0);
#pragma unroll
      for (int j = 0; j < 8; ++j) {
        const int d = d0 + j;
        *(u16*)(VtB + d * 144 + ((rr * 2) ^ (((d >> 3) & 7) << 4))) = (u16)vv[j];
      }
    }
    __syncthreads();

    const bool skip = (kt * 64) > (q0 + 31);

    f32x4 sc[2][4];
#pragma unroll
    for (int mi = 0; mi < 2; ++mi)
#pragma unroll
      for (int t = 0; t < 4; ++t) sc[mi][t] = fz;
    if (!skip) {
#pragma unroll
      for (int t = 0; t < 4; ++t)
#pragma unroll
        for (int c = 0; c < 4; ++c) {
          const int row = t * 16 + (ln & 15);
          const int cb = (c * 64 + (ln >> 4) * 16) ^ ((row & 7) << 4);
          const short8 kh8 = *(const short8*)(KhsB + row * 256 + cb);
          const short8 kl8 = *(const short8*)(KlsB + row * 256 + cb);
#pragma unroll
          for (int mi = 0; mi < 2; ++mi) {
            sc[mi][t] = MFMA(qfh[mi][c], kh8, sc[mi][t]);
            sc[mi][t] = MFMA(qfh[mi][c], kl8, sc[mi][t]);
            sc[mi][t] = MFMA(qfl[mi][c], kh8, sc[mi][t]);
          }
        }
      if (kt >= 2 * qt) {
#pragma unroll
        for (int mi = 0; mi < 2; ++mi)
#pragma unroll
          for (int t = 0; t < 4; ++t)
#pragma unroll
            for (int r = 0; r < 4; ++r) {
              const int qg = q0 + mi * 16 + (ln >> 4) * 4 + r;
              const int kg = kt * 64 + t * 16 + (ln & 15);
              if (kg > qg) sc[mi][t][r] = -1e30f;
            }
      }
    }
    __syncthreads();

    if (!skip) {
#pragma unroll
      for (int mi = 0; mi < 2; ++mi)
#pragma unroll
        for (int r = 0; r < 4; ++r) {
          float rm = fmaxf(fmaxf(sc[mi][0][r], sc[mi][1][r]),
                           fmaxf(sc[mi][2][r], sc[mi][3][r]));
          rm = rmax16(rm);
          const float mn = fmaxf(m_run[mi][r], rm);
          const float alpha = __expf(m_run[mi][r] - mn);
          m_run[mi][r] = mn;
          const int irow = mi * 16 + (ln >> 4) * 4 + r;
          float ps = 0.f;
#pragma unroll
          for (int t = 0; t < 4; ++t) {
            const float pv = __expf(sc[mi][t][r] - mn);
            ps += pv;
            *(u16*)(PlB + wv * 4608 + irow * 144 + (t * 16 + (ln & 15)) * 2) = f2bf(pv);
          }
          ps = rsum16(ps);
          l_run[mi][r] = l_run[mi][r] * alpha + ps;
#pragma unroll
          for (int n = 0; n < 8; ++n) acc_o[mi][n][r] *= alpha;
        }
    }
    asm volatile("s_waitcnt lgkmcnt(0)" ::: "memory");
    __builtin_amdgcn_sched_barrier(0);

    if (!skip) {
      short8 pf[2][2];
#pragma unroll
      for (int mi = 0; mi < 2; ++mi)
#pragma unroll
        for (int c2 = 0; c2 < 2; ++c2)
          pf[mi][c2] = *(const short8*)(PlB + wv * 4608 + (mi * 16 + (ln & 15)) * 144 +
                                        c2 * 64 + (ln >> 4) * 16);
#pragma unroll
      for (int n = 0; n < 8; ++n)
#pragma unroll
        for (int c2 = 0; c2 < 2; ++c2) {
          const int d = n * 16 + (ln & 15);
          const short8 v8 = *(const short8*)(VtB + d * 144 +
                              ((c2 * 64 + (ln >> 4) * 16) ^ (((d >> 3) & 7) << 4)));
          acc_o[0][n] = MFMA(pf[0][c2], v8, acc_o[0][n]);
          acc_o[1][n] = MFMA(pf[1][c2], v8, acc_o[1][n]);
        }
    }
    __syncthreads();
  }

  const int b = bh >> 4, h = bh & 15;
#pragma unroll
  for (int mi = 0; mi < 2; ++mi)
#pragma unroll
    for (int r = 0; r < 4; ++r) {
      const float inv = 1.f / l_run[mi][r];
      const int s = q0 + mi * 16 + (ln >> 4) * 4 + r;
#pragma unroll
      for (int n = 0; n < 8; ++n) {
        const int col = n * 16 + (ln & 15);
        ctx[((size_t)b * Sd + s) * Ed + h * Dd + col] = f2bf(acc_o[mi][n][r] * inv);
      }
    }
}

extern "C" void kernel_launch(void* const* d_in, const int* in_sizes, int n_in,
                              void* d_out, int out_size, void* d_ws, size_t ws_size,
                              hipStream_t stream) {
  (void)in_sizes; (void)n_in; (void)out_size; (void)ws_size;
  const float* x  = (const float*)d_in[0];
  const float* Wq = (const float*)d_in[1];
  const float* Wk = (const float*)d_in[2];
  const float* Wv = (const float*)d_in[3];
  const float* Wo = (const float*)d_in[4];
  const float* bo = (const float*)d_in[5];
  float* out = (float*)d_out;

  const size_t NTOK = (size_t)Bd * Sd * Ed;
  const size_t NW   = (size_t)Ed * Ed;

  char* w = (char*)d_ws;
  u16* xh = (u16*)w;  w += NTOK * 2;
  u16* xl = (u16*)w;  w += NTOK * 2;
  u16* wh = (u16*)w;  w += 3 * NW * 2;
  u16* wl = (u16*)w;  w += 3 * NW * 2;
  u16* wob = (u16*)w; w += NW * 2;
  u16* Qh = (u16*)w;  w += NTOK * 2;
  u16* Ql = (u16*)w;  w += NTOK * 2;
  u16* Kh = (u16*)w;  w += NTOK * 2;
  u16* Kl = (u16*)w;  w += NTOK * 2;
  u16* Vb = (u16*)w;  w += NTOK * 2;
  u16* ctx = (u16*)w; w += NTOK * 2;

  k_split<<<dim3(2048), 256, 0, stream>>>(x, xh, xl, (int)(NTOK / 4));
  k_split<<<dim3(1024), 256, 0, stream>>>(Wq, wh, wl, (int)(NW / 4));
  k_split<<<dim3(1024), 256, 0, stream>>>(Wk, wh + NW, wl + NW, (int)(NW / 4));
  k_split<<<dim3(1024), 256, 0, stream>>>(Wv, wh + 2 * NW, wl + 2 * NW, (int)(NW / 4));
  k_cvt<<<dim3(1024), 256, 0, stream>>>(Wo, wob, (int)(NW / 4));

  gemm_qk<<<dim3(256), 512, 0, stream>>>(xh, xl, wh, wl, wh + NW, wl + NW,
                                         Qh, Ql, Kh, Kl);
  gemm1<0><<<dim3(256), 512, 0, stream>>>(xh, wh + 2 * NW, nullptr, Vb, nullptr);

  k_attn<<<dim3(Bd * Hd, Sd / 128), 256, 0, stream>>>(Qh, Ql, Kh, Kl, Vb, ctx);

  gemm1<1><<<dim3(256), 512, 0, stream>>>(ctx, wob, bo, nullptr, out);
}

// Round 5
// 319.536 us; speedup vs baseline: 1.3442x; 1.2911x over previous
//
#include <hip/hip_runtime.h>
#include <stdint.h>
#include <stddef.h>

#define Bd 2
#define Sd 2048
#define Ed 2048
#define Hd 16
#define Dd 128

typedef unsigned short u16;
typedef _Float16 f16;
typedef __attribute__((ext_vector_type(8))) _Float16 half8;
typedef __attribute__((ext_vector_type(4))) float f32x4;

__device__ __forceinline__ u16 f2h(float f) {
  f16 h = (f16)f; return __builtin_bit_cast(u16, h);
}
__device__ __forceinline__ float h2f(u16 u) {
  return (float)__builtin_bit_cast(f16, u);
}
__device__ __forceinline__ void gll16(const void* g, void* lds) {
  __builtin_amdgcn_global_load_lds(
      (const __attribute__((address_space(1))) void*)g,
      (__attribute__((address_space(3))) void*)lds, 16, 0, 0);
}
template<int C> __device__ __forceinline__ float dppmv(float x) {
  return __builtin_bit_cast(float,
      __builtin_amdgcn_update_dpp(0, __builtin_bit_cast(int, x), C, 0xF, 0xF, false));
}
__device__ __forceinline__ float rmax16(float x) {
  x = fmaxf(x, dppmv<0x121>(x)); x = fmaxf(x, dppmv<0x122>(x));
  x = fmaxf(x, dppmv<0x124>(x)); x = fmaxf(x, dppmv<0x128>(x));
  return x;
}
__device__ __forceinline__ float rsum16(float x) {
  x += dppmv<0x121>(x); x += dppmv<0x122>(x);
  x += dppmv<0x124>(x); x += dppmv<0x128>(x);
  return x;
}
#define MFMA(a,b,c) __builtin_amdgcn_mfma_f32_16x16x32_f16((a),(b),(c),0,0,0)

#define BARRIER() do { __builtin_amdgcn_s_barrier(); __builtin_amdgcn_sched_barrier(0); } while (0)
#define LGKM(n) do { asm volatile("s_waitcnt lgkmcnt(" #n ")" ::: "memory"); __builtin_amdgcn_sched_barrier(0); } while (0)
#define VMCNT(n) do { asm volatile("s_waitcnt vmcnt(" #n ")" ::: "memory"); __builtin_amdgcn_sched_barrier(0); } while (0)

// ---------------- pre-pass: fp32 -> fp16 hi/lo split (x) and fp16 cvt (W) ----------------
__global__ void k_split(const float* __restrict__ src, u16* __restrict__ hi,
                        u16* __restrict__ lo, int n4) {
  const int stride = gridDim.x * blockDim.x;
  for (int i = blockIdx.x * blockDim.x + threadIdx.x; i < n4; i += stride) {
    const float4 v = ((const float4*)src)[i];
    const f16 h0 = (f16)v.x, h1 = (f16)v.y, h2 = (f16)v.z, h3 = (f16)v.w;
    ((ushort4*)hi)[i] = make_ushort4(__builtin_bit_cast(u16, h0), __builtin_bit_cast(u16, h1),
                                     __builtin_bit_cast(u16, h2), __builtin_bit_cast(u16, h3));
    ((ushort4*)lo)[i] = make_ushort4(f2h(v.x - (float)h0), f2h(v.y - (float)h1),
                                     f2h(v.z - (float)h2), f2h(v.w - (float)h3));
  }
}
__global__ void k_cvt(const float* __restrict__ src, u16* __restrict__ dst, int n4) {
  const int stride = gridDim.x * blockDim.x;
  for (int i = blockIdx.x * blockDim.x + threadIdx.x; i < n4; i += stride) {
    const float4 v = ((const float4*)src)[i];
    ((ushort4*)dst)[i] = make_ushort4(f2h(v.x), f2h(v.y), f2h(v.z), f2h(v.w));
  }
}

// ---------------- Q & K projection: fp16 2-pass, 256^2-tile, 8-phase ----------------
// Q = [xh|xl] . [Wh|Wh]^T  (exact x, fp16 weight), K' = 2*2048 = 4096.
// 256 blocks (z<128: Q, else K), 512 threads (8 waves, 2Mx4N), wave-tile 128x64.
__global__ __launch_bounds__(512, 2) void gemm_qk(
    const u16* __restrict__ xh, const u16* __restrict__ xl,
    const u16* __restrict__ wq, const u16* __restrict__ wk,
    u16* __restrict__ Qf, u16* __restrict__ Kf) {
  constexpr int NT = 64;  // 4096 / 64
  __shared__ __align__(16) char smem[131072];
  const int lin = blockIdx.x;
  const int z = lin >> 7;
  const int rr = lin & 127;
  const int n0 = (rr & 7) * 256;   // blockIdx%8 -> n-panel: XCD L2 locality
  const int m0 = (rr >> 3) * 256;
  const u16* wgt = z ? wk : wq;
  u16* oq = z ? Kf : Qf;
  const int tid = threadIdx.x, wv = tid >> 6, ln = tid & 63;
  const int wvm = wv >> 2, wvn = wv & 3;

  // ---- stage events: 16KB each = 2 gll per wave ----
  auto stgA = [&](int tt, int par) {
    if (tt >= NT) return;
    const u16* A = (tt >> 5) ? xl : xh;
    const int kin = (tt & 31) << 6;
    const int c = tt & 1;
    const int r8 = ln >> 3, cc = ((ln & 7) ^ r8) * 16;
#pragma unroll
    for (int e = 0; e < 2; ++e) {
      const int ch = e * 8 + wv;
      const int trow = (par + (ch >> 3) * 2) * 64 + (ch & 7) * 8;
      gll16((const char*)A + (size_t)(m0 + trow + r8) * 4096 + (size_t)kin * 2 + cc,
            smem + c * 65536 + trow * 128);
    }
  };
  auto stgB = [&](int tt, int n2) {
    if (tt >= NT) return;
    const int kin = (tt & 31) << 6;
    const int c = tt & 1;
    const int r8 = ln >> 3, cc = ((ln & 7) ^ r8) * 16;
#pragma unroll
    for (int e = 0; e < 2; ++e) {
      const int ch = e * 8 + wv;
      const int trow = (ch >> 2) * 64 + n2 * 32 + (ch & 3) * 8;
      gll16((const char*)wgt + (size_t)(n0 + trow + r8) * 4096 + (size_t)kin * 2 + cc,
            smem + c * 65536 + 32768 + trow * 128);
    }
  };
  auto ldAh = [&](int c, int h, half8 (*a)[2]) {
#pragma unroll
    for (int mm = 0; mm < 4; ++mm) {
      const int row = wvm * 128 + h * 64 + mm * 16 + (ln & 15);
#pragma unroll
      for (int s = 0; s < 2; ++s) {
        const int cb = (s * 64 + (ln >> 4) * 16) ^ ((row & 7) << 4);
        a[mm][s] = *(const half8*)(smem + c * 65536 + row * 128 + cb);
      }
    }
  };
  auto ldBh = [&](int c, int n2, half8 (*b)[2]) {
#pragma unroll
    for (int nn = 0; nn < 2; ++nn) {
      const int row = wvn * 64 + (n2 * 2 + nn) * 16 + (ln & 15);
#pragma unroll
      for (int s = 0; s < 2; ++s) {
        const int cb = (s * 64 + (ln >> 4) * 16) ^ ((row & 7) << 4);
        b[nn][s] = *(const half8*)(smem + c * 65536 + 32768 + row * 128 + cb);
      }
    }
  };

  const f32x4 fz = {0.f, 0.f, 0.f, 0.f};
  f32x4 acc[8][4];
#pragma unroll
  for (int mm = 0; mm < 8; ++mm)
#pragma unroll
    for (int nn = 0; nn < 4; ++nn) acc[mm][nn] = fz;

#define QUAD(MB, NB, AA, BB)                                                    \
  do {                                                                          \
    __builtin_amdgcn_s_setprio(1);                                              \
    _Pragma("unroll")                                                           \
    for (int mm = 0; mm < 4; ++mm)                                              \
      _Pragma("unroll")                                                         \
      for (int nn = 0; nn < 2; ++nn) {                                          \
        acc[MB + mm][NB + nn] = MFMA(AA[mm][0], BB[nn][0], acc[MB + mm][NB + nn]); \
        acc[MB + mm][NB + nn] = MFMA(AA[mm][1], BB[nn][1], acc[MB + mm][NB + nn]); \
      }                                                                         \
    __builtin_amdgcn_s_setprio(0);                                              \
  } while (0)

  // prologue: K0 complete + K1 {A-early, B0, B1}; K1's A-late staged at w=0 P1
  stgA(0, 0); stgA(0, 1); stgB(0, 0); stgB(0, 1);
  stgA(1, 0); stgB(1, 0); stgB(1, 1);
  VMCNT(6);
  BARRIER();

  for (int w = 0; w < NT; ++w) {
    const int c = w & 1;
    half8 a[4][2], b0[2][2], b1[2][2];
    // ---- P1: ds A(h0)+B(n2=0) [12]; stage A-late(w+1)
    ldAh(c, 0, a);
    ldBh(c, 0, b0);
    stgA(w + 1, 1);
    BARRIER(); LGKM(0);
    QUAD(0, 0, a, b0);
    BARRIER();
    // ---- P2: ds B(n2=1) [4]; stage A-early(w+2)
    ldBh(c, 1, b1);
    stgA(w + 2, 0);
    BARRIER(); LGKM(0);
    QUAD(0, 2, a, b1);
    BARRIER();
    // ---- P3: ds A(h1) [8]; stage B0(w+2)
    ldAh(c, 1, a);
    stgB(w + 2, 0);
    BARRIER(); LGKM(0);
    QUAD(4, 0, a, b0);
    BARRIER();
    // ---- P4: stage B1(w+2); counted vmcnt
    stgB(w + 2, 1);
    BARRIER();
    QUAD(4, 2, a, b1);
    if (w + 2 < NT) { VMCNT(6); } else { VMCNT(0); }
    BARRIER();
  }
#undef QUAD

  // epilogue: fp16 output at (B,H,S,D)
#pragma unroll
  for (int mm = 0; mm < 8; ++mm)
#pragma unroll
    for (int nn = 0; nn < 4; ++nn)
#pragma unroll
      for (int r4 = 0; r4 < 4; ++r4) {
        const int mg = m0 + wvm * 128 + mm * 16 + (ln >> 4) * 4 + r4;
        const int f = n0 + wvn * 64 + nn * 16 + (ln & 15);
        const int b = mg >> 11, s = mg & (Sd - 1);
        const int h = f >> 7, d = f & (Dd - 1);
        oq[(((size_t)b * Hd + h) * Sd + s) * Dd + d] = f2h(acc[mm][nn][r4]);
      }
}

// ---------------- single-pass fp16 GEMM, 128x256 tile, 4-phase pipeline ----------------
// MODE 0: V projection (A=xh, B=wv) -> fp16 at (B,H,S,D)
// MODE 1: out projection (A=ctx, B=wo) -> fp32 [m,f] + bias
template<int MODE>
__global__ __launch_bounds__(512, 2) void gemm1(
    const u16* __restrict__ Ap, const u16* __restrict__ Bp,
    const float* __restrict__ bias, u16* __restrict__ ob, float* __restrict__ of) {
  constexpr int NT = 32;  // 2048 / 64
  __shared__ __align__(16) char smem[98304];
  const int bid = blockIdx.x;
  const int n0 = (bid & 7) * 256;
  const int m0 = (bid >> 3) * 128;
  const int tid = threadIdx.x, wv = tid >> 6, ln = tid & 63;
  const int wvm = wv >> 2, wvn = wv & 3;

  auto stageA = [&](int tt, int c) {
    const int kin = tt << 6;
#pragma unroll
    for (int i = 0; i < 2; ++i) {
      const int l2 = i * 8192 + wv * 1024 + ln * 16;
      const int row = l2 >> 7, cb = l2 & 127;
      const int gc = cb ^ ((row & 7) << 4);
      gll16((const char*)Ap + (size_t)(m0 + row) * 4096 + (size_t)kin * 2 + gc,
            smem + c * 49152 + i * 8192 + wv * 1024);
    }
  };
  auto stageB = [&](int tt, int c) {
    const int kin = tt << 6;
#pragma unroll
    for (int i = 0; i < 4; ++i) {
      const int l2 = i * 8192 + wv * 1024 + ln * 16;
      const int row = l2 >> 7, cb = l2 & 127;
      const int gc = cb ^ ((row & 7) << 4);
      gll16((const char*)Bp + (size_t)(n0 + row) * 4096 + (size_t)kin * 2 + gc,
            smem + c * 49152 + 16384 + i * 8192 + wv * 1024);
    }
  };
  auto ldA = [&](int c, int s, half8* af) {
#pragma unroll
    for (int mm = 0; mm < 4; ++mm) {
      const int row = wvm * 64 + mm * 16 + (ln & 15);
      const int cb = (s * 64 + (ln >> 4) * 16) ^ ((row & 7) << 4);
      af[mm] = *(const half8*)(smem + c * 49152 + row * 128 + cb);
    }
  };
  auto ldB = [&](int c, int s, int p, half8* bf) {
#pragma unroll
    for (int j = 0; j < 2; ++j) {
      const int row = wvn * 64 + (p * 2 + j) * 16 + (ln & 15);
      const int cb = (s * 64 + (ln >> 4) * 16) ^ ((row & 7) << 4);
      bf[j] = *(const half8*)(smem + c * 49152 + 16384 + row * 128 + cb);
    }
  };

  const f32x4 fz = {0.f, 0.f, 0.f, 0.f};
  f32x4 acc[4][4];
#pragma unroll
  for (int mm = 0; mm < 4; ++mm)
#pragma unroll
    for (int nn = 0; nn < 4; ++nn) acc[mm][nn] = fz;

  stageA(0, 0);
  stageB(0, 0);
  stageA(1, 1);
  VMCNT(2);
  BARRIER();

  for (int t = 0; t < NT; ++t) {
    const int c = t & 1;
    const bool h1 = (t + 1 < NT), h2 = (t + 2 < NT);
    half8 af[4], bf01[2], bf23[2];
    ldA(c, 0, af);
    ldB(c, 0, 0, bf01);
    ldB(c, 0, 1, bf23);
    if (h1) stageB(t + 1, c ^ 1);
    BARRIER();
    LGKM(2);
    __builtin_amdgcn_s_setprio(1);
#pragma unroll
    for (int mm = 0; mm < 4; ++mm) {
      acc[mm][0] = MFMA(af[mm], bf01[0], acc[mm][0]);
      acc[mm][1] = MFMA(af[mm], bf01[1], acc[mm][1]);
    }
    __builtin_amdgcn_s_setprio(0);
    BARRIER();
    LGKM(0);
    __builtin_amdgcn_s_setprio(1);
#pragma unroll
    for (int mm = 0; mm < 4; ++mm) {
      acc[mm][2] = MFMA(af[mm], bf23[0], acc[mm][2]);
      acc[mm][3] = MFMA(af[mm], bf23[1], acc[mm][3]);
    }
    __builtin_amdgcn_s_setprio(0);
    BARRIER();
    ldA(c, 1, af);
    ldB(c, 1, 0, bf01);
    ldB(c, 1, 1, bf23);
    BARRIER();
    LGKM(2);
    __builtin_amdgcn_s_setprio(1);
#pragma unroll
    for (int mm = 0; mm < 4; ++mm) {
      acc[mm][0] = MFMA(af[mm], bf01[0], acc[mm][0]);
      acc[mm][1] = MFMA(af[mm], bf01[1], acc[mm][1]);
    }
    __builtin_amdgcn_s_setprio(0);
    BARRIER();
    if (h2) stageA(t + 2, c);
    LGKM(0);
    __builtin_amdgcn_s_setprio(1);
#pragma unroll
    for (int mm = 0; mm < 4; ++mm) {
      acc[mm][2] = MFMA(af[mm], bf23[0], acc[mm][2]);
      acc[mm][3] = MFMA(af[mm], bf23[1], acc[mm][3]);
    }
    __builtin_amdgcn_s_setprio(0);
    if (h2)      { VMCNT(2); }
    else if (h1) { VMCNT(0); }
    BARRIER();
  }

#pragma unroll
  for (int mm = 0; mm < 4; ++mm)
#pragma unroll
    for (int nn = 0; nn < 4; ++nn) {
      const int f = n0 + wvn * 64 + nn * 16 + (ln & 15);
      float bi = 0.f;
      if (MODE == 1) bi = bias[f];
#pragma unroll
      for (int r4 = 0; r4 < 4; ++r4) {
        const int mg = m0 + wvm * 64 + mm * 16 + (ln >> 4) * 4 + r4;
        if (MODE == 0) {
          const int b = mg >> 11, s = mg & (Sd - 1);
          const int h = f >> 7, d = f & (Dd - 1);
          ob[(((size_t)b * Hd + h) * Sd + s) * Dd + d] = f2h(acc[mm][nn][r4]);
        } else {
          of[(size_t)mg * Ed + f] = acc[mm][nn][r4] + bi;
        }
      }
    }
}

// ---------------- causal flash attention, fp16 single-pass QK (no 1/sqrt(d)) ----------------
__global__ __launch_bounds__(256, 2) void k_attn(
    const u16* __restrict__ Qf, const u16* __restrict__ Kf,
    const u16* __restrict__ Vb, u16* __restrict__ ctx) {
  __shared__ __align__(16) char smem[53248];
  char* KsB = smem;              // 16384 B  [64][128] f16, swizzled
  char* VtB = smem + 16384;      // 18432 B  [128 d][72 k] f16, swizzled
  char* PlB = smem + 34816;      // 18432 B  per-wave P slices

  const int bh = blockIdx.x;
  const int qt = (int)gridDim.y - 1 - blockIdx.y;
  const int tid = threadIdx.x, wv = tid >> 6, ln = tid & 63;
  const int q0 = qt * 128 + wv * 32;
  const size_t headoff = (size_t)bh * Sd * Dd;

  half8 qf[2][4];
#pragma unroll
  for (int mi = 0; mi < 2; ++mi)
#pragma unroll
    for (int c = 0; c < 4; ++c) {
      const size_t off = headoff + (size_t)(q0 + mi * 16 + (ln & 15)) * Dd + c * 32 + (ln >> 4) * 8;
      qf[mi][c] = *(const half8*)(Qf + off);
    }

  const f32x4 fz = {0.f, 0.f, 0.f, 0.f};
  f32x4 acc_o[2][8];
  float m_run[2][4], l_run[2][4];
#pragma unroll
  for (int mi = 0; mi < 2; ++mi) {
#pragma unroll
    for (int n = 0; n < 8; ++n) acc_o[mi][n] = fz;
#pragma unroll
    for (int r = 0; r < 4; ++r) { m_run[mi][r] = -1e30f; l_run[mi][r] = 0.f; }
  }

  const int ktmax = 2 * qt + 1;
  for (int kt = 0; kt <= ktmax; ++kt) {
    const size_t ktile = (headoff + (size_t)kt * 64 * Dd) * 2;
#pragma unroll
    for (int i = 0; i < 4; ++i) {
      const int lin = i * 4096 + wv * 1024 + ln * 16;
      const int row = lin >> 8;
      const int cb = lin & 255;
      const int gc = cb ^ ((row & 7) << 4);
      gll16((const char*)Kf + ktile + (size_t)row * 256 + gc, KsB + i * 4096 + wv * 1024);
    }
#pragma unroll
    for (int p = 0; p < 4; ++p) {
      const int rr = (tid >> 4) + 16 * p;
      const int d0 = (tid & 15) * 8;
      const ushort4 vv0 = *(const ushort4*)(Vb + headoff + (size_t)(kt * 64 + rr) * Dd + d0);
      const ushort4 vv1 = *(const ushort4*)(Vb + headoff + (size_t)(kt * 64 + rr) * Dd + d0 + 4);
      const u16 vs[8] = {vv0.x, vv0.y, vv0.z, vv0.w, vv1.x, vv1.y, vv1.z, vv1.w};
#pragma unroll
      for (int j = 0; j < 8; ++j) {
        const int d = d0 + j;
        *(u16*)(VtB + d * 144 + ((rr * 2) ^ (((d >> 3) & 7) << 4))) = vs[j];
      }
    }
    __syncthreads();

    const bool skip = (kt * 64) > (q0 + 31);

    f32x4 sc[2][4];
#pragma unroll
    for (int mi = 0; mi < 2; ++mi)
#pragma unroll
      for (int t = 0; t < 4; ++t) sc[mi][t] = fz;
    if (!skip) {
#pragma unroll
      for (int t = 0; t < 4; ++t)
#pragma unroll
        for (int c = 0; c < 4; ++c) {
          const int row = t * 16 + (ln & 15);
          const int cb = (c * 64 + (ln >> 4) * 16) ^ ((row & 7) << 4);
          const half8 kh8 = *(const half8*)(KsB + row * 256 + cb);
#pragma unroll
          for (int mi = 0; mi < 2; ++mi)
            sc[mi][t] = MFMA(qf[mi][c], kh8, sc[mi][t]);
        }
      if (kt >= 2 * qt) {
#pragma unroll
        for (int mi = 0; mi < 2; ++mi)
#pragma unroll
          for (int t = 0; t < 4; ++t)
#pragma unroll
            for (int r = 0; r < 4; ++r) {
              const int qg = q0 + mi * 16 + (ln >> 4) * 4 + r;
              const int kg = kt * 64 + t * 16 + (ln & 15);
              if (kg > qg) sc[mi][t][r] = -1e30f;
            }
      }

      // ---- online softmax (fp32, DPP row-reduce) + write P (fp16) to LDS ----
#pragma unroll
      for (int mi = 0; mi < 2; ++mi)
#pragma unroll
        for (int r = 0; r < 4; ++r) {
          float rm = fmaxf(fmaxf(sc[mi][0][r], sc[mi][1][r]),
                           fmaxf(sc[mi][2][r], sc[mi][3][r]));
          rm = rmax16(rm);
          const float mn = fmaxf(m_run[mi][r], rm);
          const float alpha = __expf(m_run[mi][r] - mn);
          m_run[mi][r] = mn;
          const int irow = mi * 16 + (ln >> 4) * 4 + r;
          float ps = 0.f;
#pragma unroll
          for (int t = 0; t < 4; ++t) {
            const float pv = __expf(sc[mi][t][r] - mn);
            ps += pv;
            *(u16*)(PlB + wv * 4608 + irow * 144 + (t * 16 + (ln & 15)) * 2) = f2h(pv);
          }
          ps = rsum16(ps);
          l_run[mi][r] = l_run[mi][r] * alpha + ps;
#pragma unroll
          for (int n = 0; n < 8; ++n) acc_o[mi][n][r] *= alpha;
        }
    }
    asm volatile("s_waitcnt lgkmcnt(0)" ::: "memory");
    __builtin_amdgcn_sched_barrier(0);

    if (!skip) {
      half8 pf[2][2];
#pragma unroll
      for (int mi = 0; mi < 2; ++mi)
#pragma unroll
        for (int c2 = 0; c2 < 2; ++c2)
          pf[mi][c2] = *(const half8*)(PlB + wv * 4608 + (mi * 16 + (ln & 15)) * 144 +
                                       c2 * 64 + (ln >> 4) * 16);
#pragma unroll
      for (int n = 0; n < 8; ++n)
#pragma unroll
        for (int c2 = 0; c2 < 2; ++c2) {
          const int d = n * 16 + (ln & 15);
          const half8 v8 = *(const half8*)(VtB + d * 144 +
                             ((c2 * 64 + (ln >> 4) * 16) ^ (((d >> 3) & 7) << 4)));
          acc_o[0][n] = MFMA(pf[0][c2], v8, acc_o[0][n]);
          acc_o[1][n] = MFMA(pf[1][c2], v8, acc_o[1][n]);
        }
    }
    __syncthreads();
  }

  const int b = bh >> 4, h = bh & 15;
#pragma unroll
  for (int mi = 0; mi < 2; ++mi)
#pragma unroll
    for (int r = 0; r < 4; ++r) {
      const float inv = 1.f / l_run[mi][r];
      const int s = q0 + mi * 16 + (ln >> 4) * 4 + r;
#pragma unroll
      for (int n = 0; n < 8; ++n) {
        const int col = n * 16 + (ln & 15);
        ctx[((size_t)b * Sd + s) * Ed + h * Dd + col] = f2h(acc_o[mi][n][r] * inv);
      }
    }
}

extern "C" void kernel_launch(void* const* d_in, const int* in_sizes, int n_in,
                              void* d_out, int out_size, void* d_ws, size_t ws_size,
                              hipStream_t stream) {
  (void)in_sizes; (void)n_in; (void)out_size; (void)ws_size;
  const float* x  = (const float*)d_in[0];
  const float* Wq = (const float*)d_in[1];
  const float* Wk = (const float*)d_in[2];
  const float* Wv = (const float*)d_in[3];
  const float* Wo = (const float*)d_in[4];
  const float* bo = (const float*)d_in[5];
  float* out = (float*)d_out;

  const size_t NTOK = (size_t)Bd * Sd * Ed;  // 8388608
  const size_t NW   = (size_t)Ed * Ed;       // 4194304

  char* w = (char*)d_ws;
  u16* xh  = (u16*)w; w += NTOK * 2;
  u16* xl  = (u16*)w; w += NTOK * 2;
  u16* wq  = (u16*)w; w += NW * 2;
  u16* wk  = (u16*)w; w += NW * 2;
  u16* wv  = (u16*)w; w += NW * 2;
  u16* wo  = (u16*)w; w += NW * 2;
  u16* Qf  = (u16*)w; w += NTOK * 2;
  u16* Kf  = (u16*)w; w += NTOK * 2;
  u16* Vf  = (u16*)w; w += NTOK * 2;
  u16* ctx = (u16*)w; w += NTOK * 2;

  k_split<<<dim3(2048), 256, 0, stream>>>(x, xh, xl, (int)(NTOK / 4));
  k_cvt<<<dim3(1024), 256, 0, stream>>>(Wq, wq, (int)(NW / 4));
  k_cvt<<<dim3(1024), 256, 0, stream>>>(Wk, wk, (int)(NW / 4));
  k_cvt<<<dim3(1024), 256, 0, stream>>>(Wv, wv, (int)(NW / 4));
  k_cvt<<<dim3(1024), 256, 0, stream>>>(Wo, wo, (int)(NW / 4));

  gemm_qk<<<dim3(256), 512, 0, stream>>>(xh, xl, wq, wk, Qf, Kf);
  gemm1<0><<<dim3(256), 512, 0, stream>>>(xh, wv, nullptr, Vf, nullptr);

  k_attn<<<dim3(Bd * Hd, Sd / 128), 256, 0, stream>>>(Qf, Kf, Vf, ctx);

  gemm1<1><<<dim3(256), 512, 0, stream>>>(ctx, wo, bo, nullptr, out);
}

// Round 6
// 258.289 us; speedup vs baseline: 1.6630x; 1.2371x over previous
//
#include <hip/hip_runtime.h>
#include <stdint.h>
#include <stddef.h>

#define Bd 2
#define Sd 2048
#define Ed 2048
#define Hd 16
#define Dd 128

typedef unsigned short u16;
typedef _Float16 f16;
typedef __attribute__((ext_vector_type(8))) _Float16 half8;
typedef __attribute__((ext_vector_type(4))) float f32x4;

__device__ __forceinline__ u16 f2h(float f) {
  f16 h = (f16)f; return __builtin_bit_cast(u16, h);
}
__device__ __forceinline__ void gll16(const void* g, void* lds) {
  __builtin_amdgcn_global_load_lds(
      (const __attribute__((address_space(1))) void*)g,
      (__attribute__((address_space(3))) void*)lds, 16, 0, 0);
}
template<int C> __device__ __forceinline__ float dppmv(float x) {
  return __builtin_bit_cast(float,
      __builtin_amdgcn_update_dpp(0, __builtin_bit_cast(int, x), C, 0xF, 0xF, false));
}
__device__ __forceinline__ float rmax16(float x) {
  x = fmaxf(x, dppmv<0x121>(x)); x = fmaxf(x, dppmv<0x122>(x));
  x = fmaxf(x, dppmv<0x124>(x)); x = fmaxf(x, dppmv<0x128>(x));
  return x;
}
__device__ __forceinline__ float rsum16(float x) {
  x += dppmv<0x121>(x); x += dppmv<0x122>(x);
  x += dppmv<0x124>(x); x += dppmv<0x128>(x);
  return x;
}
#define MFMA(a,b,c) __builtin_amdgcn_mfma_f32_16x16x32_f16((a),(b),(c),0,0,0)

#define BARRIER() do { __builtin_amdgcn_s_barrier(); __builtin_amdgcn_sched_barrier(0); } while (0)
#define LGKM(n) do { asm volatile("s_waitcnt lgkmcnt(" #n ")" ::: "memory"); __builtin_amdgcn_sched_barrier(0); } while (0)
#define VMCNT(n) do { asm volatile("s_waitcnt vmcnt(" #n ")" ::: "memory"); __builtin_amdgcn_sched_barrier(0); } while (0)

// ---------------- fused pre-pass: fp32 -> fp16 for x, Wq, Wk, Wv, Wo ----------------
__global__ void k_cvt5(const float* __restrict__ x,
                       const float* __restrict__ Wq, const float* __restrict__ Wk,
                       const float* __restrict__ Wv, const float* __restrict__ Wo,
                       u16* __restrict__ xh, u16* __restrict__ wq, u16* __restrict__ wk,
                       u16* __restrict__ wv, u16* __restrict__ wo) {
  // n4 = NTOK/4 + 4*(NW/4) = 2097152 + 4*1048576 = 6291456
  const int stride = gridDim.x * blockDim.x;
  for (int i = blockIdx.x * blockDim.x + threadIdx.x; i < 6291456; i += stride) {
    const float* s; u16* d; int j;
    if (i < 2097152) { s = x; d = xh; j = i; }
    else {
      const int t = (i - 2097152) >> 20;
      j = (i - 2097152) & 1048575;
      s = (t == 0) ? Wq : (t == 1) ? Wk : (t == 2) ? Wv : Wo;
      d = (t == 0) ? wq : (t == 1) ? wk : (t == 2) ? wv : wo;
    }
    const float4 v = ((const float4*)s)[j];
    ((ushort4*)d)[j] = make_ushort4(f2h(v.x), f2h(v.y), f2h(v.z), f2h(v.w));
  }
}

// ---------------- Q & K projection: fp16 single-pass, 256^2-tile, 8-phase ----------------
// 256 blocks (z<128: Q, else K), 512 threads (8 waves, 2Mx4N), wave-tile 128x64.
__global__ __launch_bounds__(512, 2) void gemm_qk(
    const u16* __restrict__ xh,
    const u16* __restrict__ wq, const u16* __restrict__ wk,
    u16* __restrict__ Qf, u16* __restrict__ Kf) {
  constexpr int NT = 32;  // 2048 / 64
  __shared__ __align__(16) char smem[131072];
  const int lin = blockIdx.x;
  const int z = lin >> 7;
  const int rr = lin & 127;
  const int n0 = (rr & 7) * 256;   // blockIdx%8 -> n-panel: XCD L2 locality
  const int m0 = (rr >> 3) * 256;
  const u16* wgt = z ? wk : wq;
  u16* oq = z ? Kf : Qf;
  const int tid = threadIdx.x, wv = tid >> 6, ln = tid & 63;
  const int wvm = wv >> 2, wvn = wv & 3;

  // ---- stage events: 16KB each = 2 gll per wave ----
  auto stgA = [&](int tt, int par) {
    if (tt >= NT) return;
    const int kin = tt << 6;
    const int c = tt & 1;
    const int r8 = ln >> 3, cc = ((ln & 7) ^ r8) * 16;
#pragma unroll
    for (int e = 0; e < 2; ++e) {
      const int ch = e * 8 + wv;
      const int trow = (par + (ch >> 3) * 2) * 64 + (ch & 7) * 8;
      gll16((const char*)xh + (size_t)(m0 + trow + r8) * 4096 + (size_t)kin * 2 + cc,
            smem + c * 65536 + trow * 128);
    }
  };
  auto stgB = [&](int tt, int n2) {
    if (tt >= NT) return;
    const int kin = tt << 6;
    const int c = tt & 1;
    const int r8 = ln >> 3, cc = ((ln & 7) ^ r8) * 16;
#pragma unroll
    for (int e = 0; e < 2; ++e) {
      const int ch = e * 8 + wv;
      const int trow = (ch >> 2) * 64 + n2 * 32 + (ch & 3) * 8;
      gll16((const char*)wgt + (size_t)(n0 + trow + r8) * 4096 + (size_t)kin * 2 + cc,
            smem + c * 65536 + 32768 + trow * 128);
    }
  };
  auto ldAh = [&](int c, int h, half8 (*a)[2]) {
#pragma unroll
    for (int mm = 0; mm < 4; ++mm) {
      const int row = wvm * 128 + h * 64 + mm * 16 + (ln & 15);
#pragma unroll
      for (int s = 0; s < 2; ++s) {
        const int cb = (s * 64 + (ln >> 4) * 16) ^ ((row & 7) << 4);
        a[mm][s] = *(const half8*)(smem + c * 65536 + row * 128 + cb);
      }
    }
  };
  auto ldBh = [&](int c, int n2, half8 (*b)[2]) {
#pragma unroll
    for (int nn = 0; nn < 2; ++nn) {
      const int row = wvn * 64 + (n2 * 2 + nn) * 16 + (ln & 15);
#pragma unroll
      for (int s = 0; s < 2; ++s) {
        const int cb = (s * 64 + (ln >> 4) * 16) ^ ((row & 7) << 4);
        b[nn][s] = *(const half8*)(smem + c * 65536 + 32768 + row * 128 + cb);
      }
    }
  };

  const f32x4 fz = {0.f, 0.f, 0.f, 0.f};
  f32x4 acc[8][4];
#pragma unroll
  for (int mm = 0; mm < 8; ++mm)
#pragma unroll
    for (int nn = 0; nn < 4; ++nn) acc[mm][nn] = fz;

#define QUAD(MB, NB, AA, BB)                                                    \
  do {                                                                          \
    __builtin_amdgcn_s_setprio(1);                                              \
    _Pragma("unroll")                                                           \
    for (int mm = 0; mm < 4; ++mm)                                              \
      _Pragma("unroll")                                                         \
      for (int nn = 0; nn < 2; ++nn) {                                          \
        acc[MB + mm][NB + nn] = MFMA(AA[mm][0], BB[nn][0], acc[MB + mm][NB + nn]); \
        acc[MB + mm][NB + nn] = MFMA(AA[mm][1], BB[nn][1], acc[MB + mm][NB + nn]); \
      }                                                                         \
    __builtin_amdgcn_s_setprio(0);                                              \
  } while (0)

  // prologue: K0 complete + K1 {A-early, B0, B1}; K1's A-late staged at w=0 P1
  stgA(0, 0); stgA(0, 1); stgB(0, 0); stgB(0, 1);
  stgA(1, 0); stgB(1, 0); stgB(1, 1);
  VMCNT(6);
  BARRIER();

  for (int w = 0; w < NT; ++w) {
    const int c = w & 1;
    half8 a[4][2], b0[2][2], b1[2][2];
    // ---- P1: ds A(h0)+B(n2=0) [12]; stage A-late(w+1)
    ldAh(c, 0, a);
    ldBh(c, 0, b0);
    stgA(w + 1, 1);
    BARRIER(); LGKM(0);
    QUAD(0, 0, a, b0);
    BARRIER();
    // ---- P2: ds B(n2=1) [4]; stage A-early(w+2)
    ldBh(c, 1, b1);
    stgA(w + 2, 0);
    BARRIER(); LGKM(0);
    QUAD(0, 2, a, b1);
    BARRIER();
    // ---- P3: ds A(h1) [8]; stage B0(w+2)
    ldAh(c, 1, a);
    stgB(w + 2, 0);
    BARRIER(); LGKM(0);
    QUAD(4, 0, a, b0);
    BARRIER();
    // ---- P4: stage B1(w+2); counted vmcnt
    stgB(w + 2, 1);
    BARRIER();
    QUAD(4, 2, a, b1);
    if (w + 2 < NT) { VMCNT(6); } else { VMCNT(0); }
    BARRIER();
  }
#undef QUAD

  // epilogue: fp16 output at (B,H,S,D)
#pragma unroll
  for (int mm = 0; mm < 8; ++mm)
#pragma unroll
    for (int nn = 0; nn < 4; ++nn)
#pragma unroll
      for (int r4 = 0; r4 < 4; ++r4) {
        const int mg = m0 + wvm * 128 + mm * 16 + (ln >> 4) * 4 + r4;
        const int f = n0 + wvn * 64 + nn * 16 + (ln & 15);
        const int b = mg >> 11, s = mg & (Sd - 1);
        const int h = f >> 7, d = f & (Dd - 1);
        oq[(((size_t)b * Hd + h) * Sd + s) * Dd + d] = f2h(acc[mm][nn][r4]);
      }
}

// ---------------- single-pass fp16 GEMM, 128x256 tile, 4-phase pipeline ----------------
// MODE 0: V projection (A=xh, B=wv) -> fp16 at (B,H,S,D)
// MODE 1: out projection (A=ctx, B=wo) -> fp32 [m,f] + bias
template<int MODE>
__global__ __launch_bounds__(512, 2) void gemm1(
    const u16* __restrict__ Ap, const u16* __restrict__ Bp,
    const float* __restrict__ bias, u16* __restrict__ ob, float* __restrict__ of) {
  constexpr int NT = 32;  // 2048 / 64
  __shared__ __align__(16) char smem[98304];
  const int bid = blockIdx.x;
  const int n0 = (bid & 7) * 256;
  const int m0 = (bid >> 3) * 128;
  const int tid = threadIdx.x, wv = tid >> 6, ln = tid & 63;
  const int wvm = wv >> 2, wvn = wv & 3;

  auto stageA = [&](int tt, int c) {
    const int kin = tt << 6;
#pragma unroll
    for (int i = 0; i < 2; ++i) {
      const int l2 = i * 8192 + wv * 1024 + ln * 16;
      const int row = l2 >> 7, cb = l2 & 127;
      const int gc = cb ^ ((row & 7) << 4);
      gll16((const char*)Ap + (size_t)(m0 + row) * 4096 + (size_t)kin * 2 + gc,
            smem + c * 49152 + i * 8192 + wv * 1024);
    }
  };
  auto stageB = [&](int tt, int c) {
    const int kin = tt << 6;
#pragma unroll
    for (int i = 0; i < 4; ++i) {
      const int l2 = i * 8192 + wv * 1024 + ln * 16;
      const int row = l2 >> 7, cb = l2 & 127;
      const int gc = cb ^ ((row & 7) << 4);
      gll16((const char*)Bp + (size_t)(n0 + row) * 4096 + (size_t)kin * 2 + gc,
            smem + c * 49152 + 16384 + i * 8192 + wv * 1024);
    }
  };
  auto ldA = [&](int c, int s, half8* af) {
#pragma unroll
    for (int mm = 0; mm < 4; ++mm) {
      const int row = wvm * 64 + mm * 16 + (ln & 15);
      const int cb = (s * 64 + (ln >> 4) * 16) ^ ((row & 7) << 4);
      af[mm] = *(const half8*)(smem + c * 49152 + row * 128 + cb);
    }
  };
  auto ldB = [&](int c, int s, int p, half8* bf) {
#pragma unroll
    for (int j = 0; j < 2; ++j) {
      const int row = wvn * 64 + (p * 2 + j) * 16 + (ln & 15);
      const int cb = (s * 64 + (ln >> 4) * 16) ^ ((row & 7) << 4);
      bf[j] = *(const half8*)(smem + c * 49152 + 16384 + row * 128 + cb);
    }
  };

  const f32x4 fz = {0.f, 0.f, 0.f, 0.f};
  f32x4 acc[4][4];
#pragma unroll
  for (int mm = 0; mm < 4; ++mm)
#pragma unroll
    for (int nn = 0; nn < 4; ++nn) acc[mm][nn] = fz;

  stageA(0, 0);
  stageB(0, 0);
  stageA(1, 1);
  VMCNT(2);
  BARRIER();

  for (int t = 0; t < NT; ++t) {
    const int c = t & 1;
    const bool h1 = (t + 1 < NT), h2 = (t + 2 < NT);
    half8 af[4], bf01[2], bf23[2];
    ldA(c, 0, af);
    ldB(c, 0, 0, bf01);
    ldB(c, 0, 1, bf23);
    if (h1) stageB(t + 1, c ^ 1);
    BARRIER();
    LGKM(2);
    __builtin_amdgcn_s_setprio(1);
#pragma unroll
    for (int mm = 0; mm < 4; ++mm) {
      acc[mm][0] = MFMA(af[mm], bf01[0], acc[mm][0]);
      acc[mm][1] = MFMA(af[mm], bf01[1], acc[mm][1]);
    }
    __builtin_amdgcn_s_setprio(0);
    BARRIER();
    LGKM(0);
    __builtin_amdgcn_s_setprio(1);
#pragma unroll
    for (int mm = 0; mm < 4; ++mm) {
      acc[mm][2] = MFMA(af[mm], bf23[0], acc[mm][2]);
      acc[mm][3] = MFMA(af[mm], bf23[1], acc[mm][3]);
    }
    __builtin_amdgcn_s_setprio(0);
    BARRIER();
    ldA(c, 1, af);
    ldB(c, 1, 0, bf01);
    ldB(c, 1, 1, bf23);
    BARRIER();
    LGKM(2);
    __builtin_amdgcn_s_setprio(1);
#pragma unroll
    for (int mm = 0; mm < 4; ++mm) {
      acc[mm][0] = MFMA(af[mm], bf01[0], acc[mm][0]);
      acc[mm][1] = MFMA(af[mm], bf01[1], acc[mm][1]);
    }
    __builtin_amdgcn_s_setprio(0);
    BARRIER();
    if (h2) stageA(t + 2, c);
    LGKM(0);
    __builtin_amdgcn_s_setprio(1);
#pragma unroll
    for (int mm = 0; mm < 4; ++mm) {
      acc[mm][2] = MFMA(af[mm], bf23[0], acc[mm][2]);
      acc[mm][3] = MFMA(af[mm], bf23[1], acc[mm][3]);
    }
    __builtin_amdgcn_s_setprio(0);
    if (h2)      { VMCNT(2); }
    else if (h1) { VMCNT(0); }
    BARRIER();
  }

#pragma unroll
  for (int mm = 0; mm < 4; ++mm)
#pragma unroll
    for (int nn = 0; nn < 4; ++nn) {
      const int f = n0 + wvn * 64 + nn * 16 + (ln & 15);
      float bi = 0.f;
      if (MODE == 1) bi = bias[f];
#pragma unroll
      for (int r4 = 0; r4 < 4; ++r4) {
        const int mg = m0 + wvm * 64 + mm * 16 + (ln >> 4) * 4 + r4;
        if (MODE == 0) {
          const int b = mg >> 11, s = mg & (Sd - 1);
          const int h = f >> 7, d = f & (Dd - 1);
          ob[(((size_t)b * Hd + h) * Sd + s) * Dd + d] = f2h(acc[mm][nn][r4]);
        } else {
          of[(size_t)mg * Ed + f] = acc[mm][nn][r4] + bi;
        }
      }
    }
}

// ---------------- causal flash attention, fp16 single-pass QK (no 1/sqrt(d)) ----------------
__global__ __launch_bounds__(256, 2) void k_attn(
    const u16* __restrict__ Qf, const u16* __restrict__ Kf,
    const u16* __restrict__ Vb, u16* __restrict__ ctx) {
  __shared__ __align__(16) char smem[53248];
  char* KsB = smem;              // 16384 B  [64][128] f16, swizzled
  char* VtB = smem + 16384;      // 18432 B  [128 d][72 k] f16, swizzled
  char* PlB = smem + 34816;      // 18432 B  per-wave P slices

  const int bh = blockIdx.x;
  const int qt = (int)gridDim.y - 1 - blockIdx.y;
  const int tid = threadIdx.x, wv = tid >> 6, ln = tid & 63;
  const int q0 = qt * 128 + wv * 32;
  const size_t headoff = (size_t)bh * Sd * Dd;

  half8 qf[2][4];
#pragma unroll
  for (int mi = 0; mi < 2; ++mi)
#pragma unroll
    for (int c = 0; c < 4; ++c) {
      const size_t off = headoff + (size_t)(q0 + mi * 16 + (ln & 15)) * Dd + c * 32 + (ln >> 4) * 8;
      qf[mi][c] = *(const half8*)(Qf + off);
    }

  const f32x4 fz = {0.f, 0.f, 0.f, 0.f};
  f32x4 acc_o[2][8];
  float m_run[2][4], l_run[2][4];
#pragma unroll
  for (int mi = 0; mi < 2; ++mi) {
#pragma unroll
    for (int n = 0; n < 8; ++n) acc_o[mi][n] = fz;
#pragma unroll
    for (int r = 0; r < 4; ++r) { m_run[mi][r] = -1e30f; l_run[mi][r] = 0.f; }
  }

  const int ktmax = 2 * qt + 1;
  for (int kt = 0; kt <= ktmax; ++kt) {
    const size_t ktile = (headoff + (size_t)kt * 64 * Dd) * 2;
#pragma unroll
    for (int i = 0; i < 4; ++i) {
      const int lin = i * 4096 + wv * 1024 + ln * 16;
      const int row = lin >> 8;
      const int cb = lin & 255;
      const int gc = cb ^ ((row & 7) << 4);
      gll16((const char*)Kf + ktile + (size_t)row * 256 + gc, KsB + i * 4096 + wv * 1024);
    }
#pragma unroll
    for (int p = 0; p < 4; ++p) {
      const int rr = (tid >> 4) + 16 * p;
      const int d0 = (tid & 15) * 8;
      const ushort4 vv0 = *(const ushort4*)(Vb + headoff + (size_t)(kt * 64 + rr) * Dd + d0);
      const ushort4 vv1 = *(const ushort4*)(Vb + headoff + (size_t)(kt * 64 + rr) * Dd + d0 + 4);
      const u16 vs[8] = {vv0.x, vv0.y, vv0.z, vv0.w, vv1.x, vv1.y, vv1.z, vv1.w};
#pragma unroll
      for (int j = 0; j < 8; ++j) {
        const int d = d0 + j;
        *(u16*)(VtB + d * 144 + ((rr * 2) ^ (((d >> 3) & 7) << 4))) = vs[j];
      }
    }
    __syncthreads();

    const bool skip = (kt * 64) > (q0 + 31);

    f32x4 sc[2][4];
#pragma unroll
    for (int mi = 0; mi < 2; ++mi)
#pragma unroll
      for (int t = 0; t < 4; ++t) sc[mi][t] = fz;
    if (!skip) {
#pragma unroll
      for (int t = 0; t < 4; ++t)
#pragma unroll
        for (int c = 0; c < 4; ++c) {
          const int row = t * 16 + (ln & 15);
          const int cb = (c * 64 + (ln >> 4) * 16) ^ ((row & 7) << 4);
          const half8 kh8 = *(const half8*)(KsB + row * 256 + cb);
#pragma unroll
          for (int mi = 0; mi < 2; ++mi)
            sc[mi][t] = MFMA(qf[mi][c], kh8, sc[mi][t]);
        }
      if (kt >= 2 * qt) {
#pragma unroll
        for (int mi = 0; mi < 2; ++mi)
#pragma unroll
          for (int t = 0; t < 4; ++t)
#pragma unroll
            for (int r = 0; r < 4; ++r) {
              const int qg = q0 + mi * 16 + (ln >> 4) * 4 + r;
              const int kg = kt * 64 + t * 16 + (ln & 15);
              if (kg > qg) sc[mi][t][r] = -1e30f;
            }
      }

      // ---- online softmax (fp32, DPP row-reduce) + write P (fp16) to LDS ----
#pragma unroll
      for (int mi = 0; mi < 2; ++mi)
#pragma unroll
        for (int r = 0; r < 4; ++r) {
          float rm = fmaxf(fmaxf(sc[mi][0][r], sc[mi][1][r]),
                           fmaxf(sc[mi][2][r], sc[mi][3][r]));
          rm = rmax16(rm);
          const float mn = fmaxf(m_run[mi][r], rm);
          const float alpha = __expf(m_run[mi][r] - mn);
          m_run[mi][r] = mn;
          const int irow = mi * 16 + (ln >> 4) * 4 + r;
          float ps = 0.f;
#pragma unroll
          for (int t = 0; t < 4; ++t) {
            const float pv = __expf(sc[mi][t][r] - mn);
            ps += pv;
            *(u16*)(PlB + wv * 4608 + irow * 144 + (t * 16 + (ln & 15)) * 2) = f2h(pv);
          }
          ps = rsum16(ps);
          l_run[mi][r] = l_run[mi][r] * alpha + ps;
#pragma unroll
          for (int n = 0; n < 8; ++n) acc_o[mi][n][r] *= alpha;
        }
    }
    asm volatile("s_waitcnt lgkmcnt(0)" ::: "memory");
    __builtin_amdgcn_sched_barrier(0);

    if (!skip) {
      half8 pf[2][2];
#pragma unroll
      for (int mi = 0; mi < 2; ++mi)
#pragma unroll
        for (int c2 = 0; c2 < 2; ++c2)
          pf[mi][c2] = *(const half8*)(PlB + wv * 4608 + (mi * 16 + (ln & 15)) * 144 +
                                       c2 * 64 + (ln >> 4) * 16);
#pragma unroll
      for (int n = 0; n < 8; ++n)
#pragma unroll
        for (int c2 = 0; c2 < 2; ++c2) {
          const int d = n * 16 + (ln & 15);
          const half8 v8 = *(const half8*)(VtB + d * 144 +
                             ((c2 * 64 + (ln >> 4) * 16) ^ (((d >> 3) & 7) << 4)));
          acc_o[0][n] = MFMA(pf[0][c2], v8, acc_o[0][n]);
          acc_o[1][n] = MFMA(pf[1][c2], v8, acc_o[1][n]);
        }
    }
    __syncthreads();
  }

  const int b = bh >> 4, h = bh & 15;
#pragma unroll
  for (int mi = 0; mi < 2; ++mi)
#pragma unroll
    for (int r = 0; r < 4; ++r) {
      const float inv = 1.f / l_run[mi][r];
      const int s = q0 + mi * 16 + (ln >> 4) * 4 + r;
#pragma unroll
      for (int n = 0; n < 8; ++n) {
        const int col = n * 16 + (ln & 15);
        ctx[((size_t)b * Sd + s) * Ed + h * Dd + col] = f2h(acc_o[mi][n][r] * inv);
      }
    }
}

extern "C" void kernel_launch(void* const* d_in, const int* in_sizes, int n_in,
                              void* d_out, int out_size, void* d_ws, size_t ws_size,
                              hipStream_t stream) {
  (void)in_sizes; (void)n_in; (void)out_size; (void)ws_size;
  const float* x  = (const float*)d_in[0];
  const float* Wq = (const float*)d_in[1];
  const float* Wk = (const float*)d_in[2];
  const float* Wv = (const float*)d_in[3];
  const float* Wo = (const float*)d_in[4];
  const float* bo = (const float*)d_in[5];
  float* out = (float*)d_out;

  const size_t NTOK = (size_t)Bd * Sd * Ed;  // 8388608
  const size_t NW   = (size_t)Ed * Ed;       // 4194304

  char* w = (char*)d_ws;
  u16* xh  = (u16*)w; w += NTOK * 2;
  u16* wq  = (u16*)w; w += NW * 2;
  u16* wk  = (u16*)w; w += NW * 2;
  u16* wv  = (u16*)w; w += NW * 2;
  u16* wo  = (u16*)w; w += NW * 2;
  u16* Qf  = (u16*)w; w += NTOK * 2;
  u16* Kf  = (u16*)w; w += NTOK * 2;
  u16* Vf  = (u16*)w; w += NTOK * 2;
  u16* ctx = (u16*)w; w += NTOK * 2;

  k_cvt5<<<dim3(2048), 256, 0, stream>>>(x, Wq, Wk, Wv, Wo, xh, wq, wk, wv, wo);

  gemm_qk<<<dim3(256), 512, 0, stream>>>(xh, wq, wk, Qf, Kf);
  gemm1<0><<<dim3(256), 512, 0, stream>>>(xh, wv, nullptr, Vf, nullptr);

  k_attn<<<dim3(Bd * Hd, Sd / 128), 256, 0, stream>>>(Qf, Kf, Vf, ctx);

  gemm1<1><<<dim3(256), 512, 0, stream>>>(ctx, wo, bo, nullptr, out);
}